// Round 1
// baseline (1311.904 us; speedup 1.0000x reference)
//
#include <hip/hip_runtime.h>
#include <hip/hip_bf16.h>

#define A_TOTAL 76725
#define NCLS 90
#define KTOP 5000u
#define CAP 5120
#define MAXT 100
#define KTHR 0x3D4CCCCDu   /* bits of 0.05f */

__device__ __forceinline__ unsigned long long pack_key(unsigned k, unsigned i) {
  return ((unsigned long long)k << 32) | (unsigned long long)(0xFFFFFFFFu - i);
}

// ---------------- decode + clip ----------------
__global__ void decode_kernel(
    const float* __restrict__ bx0, const float* __restrict__ bx1, const float* __restrict__ bx2,
    const float* __restrict__ bx3, const float* __restrict__ bx4,
    const float* __restrict__ an0, const float* __restrict__ an1, const float* __restrict__ an2,
    const float* __restrict__ an3, const float* __restrict__ an4,
    const float* __restrict__ img, float* __restrict__ boxes)
{
  int t = blockIdx.x * blockDim.x + threadIdx.x;
  if (t >= 2 * A_TOTAL) return;
  int b = t / A_TOTAL, a = t % A_TOTAL;
  const float* bp; const float* ap; int al; int nl;
  if (a < 57600)      { bp = bx0; ap = an0; al = a;          nl = 57600; }
  else if (a < 72000) { bp = bx1; ap = an1; al = a - 57600;  nl = 14400; }
  else if (a < 75600) { bp = bx2; ap = an2; al = a - 72000;  nl = 3600;  }
  else if (a < 76500) { bp = bx3; ap = an3; al = a - 75600;  nl = 900;   }
  else                { bp = bx4; ap = an4; al = a - 76500;  nl = 225;   }
  float4 e  = *(const float4*)(bp + ((size_t)b * nl + al) * 4);
  float4 an = *(const float4*)(ap + ((size_t)b * nl + al) * 4);
  const float CLIP = 4.135166556742356f; // log(1000/16)
  float ah  = an.z - an.x + 1.0f;
  float aw  = an.w - an.y + 1.0f;
  float ayc = an.x + 0.5f * ah;
  float axc = an.y + 0.5f * aw;
  float dh = fminf(e.z, CLIP), dw = fminf(e.w, CLIP);
  float yc = e.x * ah + ayc;
  float xc = e.y * aw + axc;
  float h  = expf(dh) * ah;
  float w  = expf(dw) * aw;
  float ymin = yc - 0.5f * h;
  float xmin = xc - 0.5f * w;
  float ymax = ymin + h - 1.0f;
  float xmax = xmin + w - 1.0f;
  float H = img[b * 2 + 0], W = img[b * 2 + 1];
  float4 o;
  o.x = fminf(fmaxf(ymin, 0.0f), H);
  o.y = fminf(fmaxf(xmin, 0.0f), W);
  o.z = fminf(fmaxf(ymax, 0.0f), H);
  o.w = fminf(fmaxf(xmax, 0.0f), W);
  *(float4*)(boxes + (size_t)t * 4) = o;
}

// ---------------- sigmoid + transpose to [B,90,A] ----------------
__global__ void transpose_kernel(const float* __restrict__ cls, int n, int base, int tiles,
                                 float* __restrict__ scores_t)
{
  __shared__ float lds[64 * 91];
  int blk = blockIdx.x;
  int b = blk / tiles, tile = blk % tiles;
  int a0 = tile * 64;
  int cnt = n - a0; if (cnt > 64) cnt = 64;
  const float* src = cls + ((size_t)b * n + a0) * 91;
  int total = cnt * 91;
  for (int i = threadIdx.x; i < total; i += 256) lds[i] = src[i];
  __syncthreads();
  for (int j = threadIdx.x; j < NCLS * 64; j += 256) {
    int c = j >> 6, a = j & 63;
    if (a < cnt) {
      float x = lds[a * 91 + c + 1];
      scores_t[((size_t)(b * NCLS + c)) * A_TOTAL + base + a0 + a] = 1.0f / (1.0f + expf(-x));
    }
  }
}

// ---------------- per-lane radix-select top-5000 + greedy NMS ----------------
__global__ __launch_bounds__(256) void select_nms_kernel(
    const float* __restrict__ scores_t, const float* __restrict__ boxes,
    float* __restrict__ nms_s, float* __restrict__ nms_b)
{
  __shared__ unsigned long long cand[CAP];
  __shared__ float4 cbox[CAP];
  __shared__ unsigned hist[2048];
  __shared__ unsigned eq[1024];
  __shared__ unsigned sh_b1, sh_b2, sh_r, sh_K, sh_eneed, sh_cnt, sh_ecnt;
  __shared__ unsigned long long wred[4];
  __shared__ unsigned long long winsh;
  __shared__ float4 wboxsh;

  int tid = threadIdx.x;
  int lane = blockIdx.x;           // b*90 + c
  int b = lane / NCLS;
  const float* S = scores_t + (size_t)lane * A_TOTAL;
  const float4* boxes4 = (const float4*)boxes;

  // ---- pass 1: bits[31:21] ----
  for (int i = tid; i < 2048; i += 256) hist[i] = 0;
  __syncthreads();
  for (int i = tid; i < A_TOTAL; i += 256)
    atomicAdd(&hist[__float_as_uint(S[i]) >> 21], 1u);
  __syncthreads();
  if (tid == 0) {
    unsigned cum = 0, bsel = 0, g = 0;
    for (int i = 2047; i >= 0; --i) {
      unsigned h = hist[i];
      if (cum + h >= KTOP) { bsel = (unsigned)i; g = cum; break; }
      cum += h;
    }
    sh_b1 = bsel; sh_r = KTOP - g;
  }
  __syncthreads();
  unsigned b1 = sh_b1, R1 = sh_r;

  // ---- pass 2: bits[20:10] within b1 ----
  for (int i = tid; i < 2048; i += 256) hist[i] = 0;
  __syncthreads();
  for (int i = tid; i < A_TOTAL; i += 256) {
    unsigned k = __float_as_uint(S[i]);
    if ((k >> 21) == b1) atomicAdd(&hist[(k >> 10) & 2047u], 1u);
  }
  __syncthreads();
  if (tid == 0) {
    unsigned cum = 0, bsel = 0, g = 0;
    for (int i = 2047; i >= 0; --i) {
      unsigned h = hist[i];
      if (cum + h >= R1) { bsel = (unsigned)i; g = cum; break; }
      cum += h;
    }
    sh_b2 = bsel; sh_r = R1 - g;
  }
  __syncthreads();
  unsigned b2 = sh_b2, R2 = sh_r;
  unsigned pref = (b1 << 11) | b2;

  // ---- pass 3: bits[9:0] within (b1,b2) ----
  for (int i = tid; i < 1024; i += 256) hist[i] = 0;
  __syncthreads();
  for (int i = tid; i < A_TOTAL; i += 256) {
    unsigned k = __float_as_uint(S[i]);
    if ((k >> 10) == pref) atomicAdd(&hist[k & 1023u], 1u);
  }
  __syncthreads();
  if (tid == 0) {
    unsigned cum = 0, bsel = 0, g = 0;
    for (int i = 1023; i >= 0; --i) {
      unsigned h = hist[i];
      if (cum + h >= R2) { bsel = (unsigned)i; g = cum; break; }
      cum += h;
    }
    unsigned K = (b1 << 21) | (b2 << 10) | bsel;
    unsigned eneed = R2 - g;
    if (K < KTHR) { K = KTHR - 1u; eneed = 0; }  // threshold dominates: take all >= 0.05f (< 5000 of them)
    sh_K = K; sh_eneed = eneed;
    sh_cnt = 0; sh_ecnt = 0;
  }
  __syncthreads();
  unsigned K = sh_K, eneed = sh_eneed;

  // ---- compaction ----
  for (int i = tid; i < A_TOTAL; i += 256) {
    unsigned k = __float_as_uint(S[i]);
    if (k > K) {
      unsigned p = atomicAdd(&sh_cnt, 1u);
      if (p < CAP) {
        cand[p] = pack_key(k, (unsigned)i);
        cbox[p] = boxes4[(size_t)b * A_TOTAL + i];
      }
    } else if (eneed > 0 && k == K) {
      unsigned e2 = atomicAdd(&sh_ecnt, 1u);
      if (e2 < 1024) eq[e2] = (unsigned)i;
    }
  }
  __syncthreads();
  unsigned G = sh_cnt; if (G > (unsigned)CAP) G = CAP;
  unsigned E = sh_ecnt; if (E > 1024u) E = 1024u;
  unsigned M = G;
  if (eneed > 0) {
    unsigned take = eneed < E ? eneed : E;
    if (take < E) {
      for (int i = tid; i < 1024; i += 256) if ((unsigned)i >= E) eq[i] = 0xFFFFFFFFu;
      for (unsigned kk = 2; kk <= 1024; kk <<= 1)
        for (unsigned jj = kk >> 1; jj > 0; jj >>= 1) {
          __syncthreads();
          for (unsigned i = tid; i < 1024; i += 256) {
            unsigned ixj = i ^ jj;
            if (ixj > i) {
              unsigned x = eq[i], y = eq[ixj];
              bool up = ((i & kk) == 0);
              if (up ? (x > y) : (x < y)) { eq[i] = y; eq[ixj] = x; }
            }
          }
        }
      __syncthreads();
    }
    for (unsigned j = tid; j < take; j += 256) {
      unsigned i = eq[j];
      cand[G + j] = pack_key(K, i);
      cbox[G + j] = boxes4[(size_t)b * A_TOTAL + i];
    }
    M = G + take;
  }
  for (int s = (int)M + tid; s < CAP; s += 256) cand[s] = 0ULL;
  __syncthreads();

  // ---- greedy NMS: 100 x (argmax + IoU suppress) ----
  float* outS = nms_s + (size_t)lane * MAXT;
  float* outB = nms_b + (size_t)lane * MAXT * 4;
  for (int pick = 0; pick < MAXT; ++pick) {
    unsigned long long m = 0;
    #pragma unroll
    for (int j = 0; j < 20; ++j) {
      unsigned long long v = cand[tid + j * 256];
      if (v > m) m = v;
    }
    #pragma unroll
    for (int off = 32; off; off >>= 1) {
      unsigned long long o = __shfl_xor(m, off);
      if (o > m) m = o;
    }
    if ((tid & 63) == 0) wred[tid >> 6] = m;
    __syncthreads();
    if (tid == 0) {
      unsigned long long w = wred[0];
      if (wred[1] > w) w = wred[1];
      if (wred[2] > w) w = wred[2];
      if (wred[3] > w) w = wred[3];
      winsh = w;
    }
    __syncthreads();
    unsigned long long win = winsh;
    if (win == 0ULL) {               // no active candidates left -> pad like reference
      for (int p = pick + tid; p < MAXT; p += 256) {
        outS[p] = -1.0f;
        *(float4*)(outB + p * 4) = make_float4(0.f, 0.f, 0.f, 0.f);
      }
      break;
    }
    #pragma unroll
    for (int j = 0; j < 20; ++j) {
      int s = tid + j * 256;
      if (cand[s] == win) {          // unique owner (idx packed)
        cand[s] = 0ULL;
        float4 wb = cbox[s];
        wboxsh = wb;
        outS[pick] = __uint_as_float((unsigned)(win >> 32));
        *(float4*)(outB + pick * 4) = wb;
      }
    }
    __syncthreads();
    float4 pb = wboxsh;
    float pa = (pb.z - pb.x) * (pb.w - pb.y);
    #pragma unroll
    for (int j = 0; j < 20; ++j) {
      int s = tid + j * 256;
      unsigned long long v = cand[s];
      if (v != 0ULL) {
        float4 bb = cbox[s];
        float yy1 = fmaxf(pb.x, bb.x);
        float xx1 = fmaxf(pb.y, bb.y);
        float yy2 = fminf(pb.z, bb.z);
        float xx2 = fminf(pb.w, bb.w);
        float inter = fmaxf(yy2 - yy1, 0.0f) * fmaxf(xx2 - xx1, 0.0f);
        float aj = (bb.z - bb.x) * (bb.w - bb.y);
        float iou = inter / (pa + aj - inter + 1e-8f);
        if (iou > 0.3f) cand[s] = 0ULL;
      }
    }
    __syncthreads();
  }
}

// ---------------- final per-batch top-100 merge of 90 sorted lists ----------------
__global__ void merge_kernel(const float* __restrict__ nms_s, const float* __restrict__ nms_b,
                             float* __restrict__ out_b, float* __restrict__ out_s,
                             float* __restrict__ out_c, float* __restrict__ out_v)
{
  int b = blockIdx.x, tid = threadIdx.x;
  __shared__ int head[NCLS];
  __shared__ unsigned long long keys[128];
  __shared__ unsigned long long winsh;
  __shared__ int validsh;
  if (tid < NCLS) head[tid] = 0;
  if (tid == 0) validsh = 0;
  __syncthreads();
  for (int t = 0; t < MAXT; ++t) {
    unsigned long long k = 0;
    if (tid < NCLS) {
      int h = head[tid];
      if (h < MAXT) {
        float s = nms_s[((size_t)b * NCLS + tid) * MAXT + h];
        unsigned u = __float_as_uint(s);
        u = (u & 0x80000000u) ? ~u : (u | 0x80000000u);   // orderable transform
        unsigned flat = (unsigned)(tid * MAXT + h);
        k = ((unsigned long long)u << 32) | (unsigned long long)(0xFFFFFFFFu - flat);
      }
    }
    keys[tid] = k;
    __syncthreads();
    if (tid < 64) {
      unsigned long long m = keys[tid] > keys[tid + 64] ? keys[tid] : keys[tid + 64];
      #pragma unroll
      for (int off = 32; off; off >>= 1) {
        unsigned long long o = __shfl_xor(m, off);
        if (o > m) m = o;
      }
      if (tid == 0) winsh = m;
    }
    __syncthreads();
    if (tid == 0) {
      unsigned long long win = winsh;
      unsigned u = (unsigned)(win >> 32);
      unsigned bits = (u & 0x80000000u) ? (u ^ 0x80000000u) : ~u;
      float s = __uint_as_float(bits);
      unsigned flat = 0xFFFFFFFFu - (unsigned)(win & 0xFFFFFFFFu);
      int cls = (int)(flat / MAXT), pos = (int)(flat % MAXT);
      out_s[b * MAXT + t] = s;
      const float* bbp = nms_b + (((size_t)b * NCLS + cls) * MAXT + pos) * 4;
      *(float4*)(out_b + ((size_t)b * MAXT + t) * 4) = *(const float4*)bbp;
      out_c[b * MAXT + t] = (float)(cls + 1);
      if (s > -1.0f) validsh++;
      head[cls] = head[cls] + 1;
    }
    __syncthreads();
  }
  if (tid == 0) out_v[b] = (float)validsh;
}

extern "C" void kernel_launch(void* const* d_in, const int* in_sizes, int n_in,
                              void* d_out, int out_size, void* d_ws, size_t ws_size,
                              hipStream_t stream)
{
  const float* box[5]; const float* cls[5]; const float* anc[5];
  bool interleaved = (in_sizes[1] == 2 * 57600 * 91);   // setup_inputs dict order
  if (interleaved) {
    for (int l = 0; l < 5; ++l) {
      box[l] = (const float*)d_in[3 * l + 0];
      cls[l] = (const float*)d_in[3 * l + 1];
      anc[l] = (const float*)d_in[3 * l + 2];
    }
  } else {                                               // reference-signature order fallback
    for (int l = 0; l < 5; ++l) {
      box[l] = (const float*)d_in[l];
      cls[l] = (const float*)d_in[5 + l];
      anc[l] = (const float*)d_in[10 + l];
    }
  }
  const float* img = (const float*)d_in[15];

  float* ws = (float*)d_ws;
  float* boxes_ws = ws;                    // 2*76725*4      = 613800 f
  float* scores_t = boxes_ws + 613800;     // 2*90*76725     = 13810500 f
  float* nms_s    = scores_t + 13810500;   // 180*100        = 18000 f
  float* nms_b    = nms_s + 18000;         // 180*100*4      = 72000 f

  decode_kernel<<<(2 * A_TOTAL + 255) / 256, 256, 0, stream>>>(
      box[0], box[1], box[2], box[3], box[4],
      anc[0], anc[1], anc[2], anc[3], anc[4], img, boxes_ws);

  const int ns[5]    = {57600, 14400, 3600, 900, 225};
  const int bases[5] = {0, 57600, 72000, 75600, 76500};
  for (int l = 0; l < 5; ++l) {
    int tiles = (ns[l] + 63) / 64;
    transpose_kernel<<<2 * tiles, 256, 0, stream>>>(cls[l], ns[l], bases[l], tiles, scores_t);
  }

  select_nms_kernel<<<180, 256, 0, stream>>>(scores_t, boxes_ws, nms_s, nms_b);

  float* out_b = (float*)d_out;  // [2][100][4]
  float* out_s = out_b + 800;    // [2][100]
  float* out_c = out_s + 200;    // [2][100] (classes as float)
  float* out_v = out_c + 200;    // [2]
  merge_kernel<<<2, 128, 0, stream>>>(nms_s, nms_b, out_b, out_s, out_c, out_v);
}

// Round 2
// 386.300 us; speedup vs baseline: 3.3961x; 3.3961x over previous
//
#include <hip/hip_runtime.h>
#include <hip/hip_bf16.h>

typedef unsigned long long u64;
typedef unsigned int u32;

#define A_TOTAL 76725
#define NCLS 90
#define KTOP 5000u
#define MAXT 100
#define KTHR 0x3D4CCCCDu   /* bits of 0.05f */
#define STH 1024           /* select kernel threads */

__device__ __forceinline__ u64 pack_key(u32 k, u32 i) {
  return ((u64)k << 32) | (u64)(0xFFFFFFFFu - i);
}

// ---------------- decode + clip ----------------
__global__ void decode_kernel(
    const float* __restrict__ bx0, const float* __restrict__ bx1, const float* __restrict__ bx2,
    const float* __restrict__ bx3, const float* __restrict__ bx4,
    const float* __restrict__ an0, const float* __restrict__ an1, const float* __restrict__ an2,
    const float* __restrict__ an3, const float* __restrict__ an4,
    const float* __restrict__ img, float* __restrict__ boxes)
{
  int t = blockIdx.x * blockDim.x + threadIdx.x;
  if (t >= 2 * A_TOTAL) return;
  int b = t / A_TOTAL, a = t % A_TOTAL;
  const float* bp; const float* ap; int al; int nl;
  if (a < 57600)      { bp = bx0; ap = an0; al = a;          nl = 57600; }
  else if (a < 72000) { bp = bx1; ap = an1; al = a - 57600;  nl = 14400; }
  else if (a < 75600) { bp = bx2; ap = an2; al = a - 72000;  nl = 3600;  }
  else if (a < 76500) { bp = bx3; ap = an3; al = a - 75600;  nl = 900;   }
  else                { bp = bx4; ap = an4; al = a - 76500;  nl = 225;   }
  float4 e  = *(const float4*)(bp + ((size_t)b * nl + al) * 4);
  float4 an = *(const float4*)(ap + ((size_t)b * nl + al) * 4);
  const float CLIP = 4.135166556742356f; // log(1000/16)
  float ah  = an.z - an.x + 1.0f;
  float aw  = an.w - an.y + 1.0f;
  float ayc = an.x + 0.5f * ah;
  float axc = an.y + 0.5f * aw;
  float dh = fminf(e.z, CLIP), dw = fminf(e.w, CLIP);
  float yc = e.x * ah + ayc;
  float xc = e.y * aw + axc;
  float h  = expf(dh) * ah;
  float w  = expf(dw) * aw;
  float ymin = yc - 0.5f * h;
  float xmin = xc - 0.5f * w;
  float ymax = ymin + h - 1.0f;
  float xmax = xmin + w - 1.0f;
  float H = img[b * 2 + 0], W = img[b * 2 + 1];
  float4 o;
  o.x = fminf(fmaxf(ymin, 0.0f), H);
  o.y = fminf(fmaxf(xmin, 0.0f), W);
  o.z = fminf(fmaxf(ymax, 0.0f), H);
  o.w = fminf(fmaxf(xmax, 0.0f), W);
  *(float4*)(boxes + (size_t)t * 4) = o;
}

// ---------------- sigmoid + transpose to [B,90,A], all levels fused ----------------
__global__ void transpose_kernel(
    const float* __restrict__ c3, const float* __restrict__ c4, const float* __restrict__ c5,
    const float* __restrict__ c6, const float* __restrict__ c7, float* __restrict__ scores_t)
{
  __shared__ float lds[64 * 91];
  int blk = blockIdx.x;
  int lvl, local;
  if      (blk < 1800) { lvl = 0; local = blk; }
  else if (blk < 2250) { lvl = 1; local = blk - 1800; }
  else if (blk < 2364) { lvl = 2; local = blk - 2250; }
  else if (blk < 2394) { lvl = 3; local = blk - 2364; }
  else                 { lvl = 4; local = blk - 2394; }
  const int ns[5]    = {57600, 14400, 3600, 900, 225};
  const int bases[5] = {0, 57600, 72000, 75600, 76500};
  const int tl[5]    = {900, 225, 57, 15, 4};
  const float* cls = (lvl == 0) ? c3 : (lvl == 1) ? c4 : (lvl == 2) ? c5 : (lvl == 3) ? c6 : c7;
  int n = ns[lvl], base = bases[lvl], tiles = tl[lvl];
  int b = local / tiles, tile = local % tiles;
  int a0 = tile * 64;
  int cnt = n - a0; if (cnt > 64) cnt = 64;
  const float* src = cls + ((size_t)b * n + a0) * 91;
  int total = cnt * 91;
  for (int i = threadIdx.x; i < total; i += 256) lds[i] = src[i];
  __syncthreads();
  for (int j = threadIdx.x; j < NCLS * 64; j += 256) {
    int c = j >> 6, a = j & 63;
    if (a < cnt) {
      float x = lds[a * 91 + c + 1];
      scores_t[((size_t)(b * NCLS + c)) * A_TOTAL + base + a0 + a] = 1.0f / (1.0f + expf(-x));
    }
  }
}

// ---------------- per-lane radix-select top-5000 + register-resident greedy NMS ----------------
__global__ __launch_bounds__(STH) void select_nms_kernel(
    const float* __restrict__ scores_t, const float* __restrict__ boxes,
    float* __restrict__ nms_s, float* __restrict__ nms_b)
{
  __shared__ u32 hist[4096];            // 16 KB
  __shared__ u64 listA[5120];           // 40 KB: strictly above boundary bucket
  __shared__ u64 listE[2048];           // 16 KB: boundary-bucket elements
  __shared__ u64 partial[16];
  __shared__ u64 winsh;
  __shared__ u32 sh_B, sh_B2, sh_cntA, sh_cntE;

  int tid = threadIdx.x;
  int lane_id = blockIdx.x;             // b*90 + c
  int b = lane_id / NCLS;
  const float* S = scores_t + (size_t)lane_id * A_TOTAL;
  const float4* boxes4 = (const float4*)boxes;

  // ---- pass 1: 4096-bucket histogram on key bits [30:19] ----
  for (int i = tid; i < 4096; i += STH) hist[i] = 0;
  __syncthreads();
  for (int i = tid; i < A_TOTAL; i += STH)
    atomicAdd(&hist[__float_as_uint(S[i]) >> 19], 1u);
  __syncthreads();

  // ---- cutoff scan (wave 0, parallel) ----
  if (tid < 64) {
    int base = 4095 - tid * 64;
    u32 s = 0;
    #pragma unroll
    for (int j = 0; j < 64; ++j) s += hist[base - j];
    u32 incl = s;
    #pragma unroll
    for (int off = 1; off < 64; off <<= 1) {
      u32 o = __shfl_up(incl, off, 64);
      if (tid >= off) incl += o;
    }
    u32 excl = incl - s;
    if (excl < KTOP && incl >= KTOP) {       // unique crossing lane
      u32 cum = excl; int bb = base;
      for (;; --bb) { cum += hist[bb]; if (cum >= KTOP) break; }
      sh_B = (u32)bb;
    }
  }
  if (tid == 0) { sh_cntA = 0; sh_cntE = 0; }
  __syncthreads();
  u32 B = sh_B;

  // ---- pass 2: collect ----
  for (int i = tid; i < A_TOTAL; i += STH) {
    u32 k = __float_as_uint(S[i]);
    u32 bkt = k >> 19;
    if (bkt > B) {
      u32 p = atomicAdd(&sh_cntA, 1u);
      if (p < 5120u) listA[p] = pack_key(k, (u32)i);
    } else if (bkt == B) {
      u32 p = atomicAdd(&sh_cntE, 1u);
      if (p < 2048u) listE[p] = pack_key(k, (u32)i);
    }
  }
  __syncthreads();
  u32 g = sh_cntA, h = sh_cntE;

  // ---- rare: boundary bucket overflowed -> refine on bits [18:7] ----
  if (h > 2048u) {
    for (int i = tid; i < 4096; i += STH) hist[i] = 0;
    if (tid == 0) sh_cntE = 0;
    __syncthreads();
    for (int i = tid; i < A_TOTAL; i += STH) {
      u32 k = __float_as_uint(S[i]);
      if ((k >> 19) == B) atomicAdd(&hist[(k >> 7) & 0xFFFu], 1u);
    }
    __syncthreads();
    u32 R1 = KTOP - g;
    if (tid < 64) {
      int base = 4095 - tid * 64;
      u32 s = 0;
      #pragma unroll
      for (int j = 0; j < 64; ++j) s += hist[base - j];
      u32 incl = s;
      #pragma unroll
      for (int off = 1; off < 64; off <<= 1) {
        u32 o = __shfl_up(incl, off, 64);
        if (tid >= off) incl += o;
      }
      u32 excl = incl - s;
      if (excl < R1 && incl >= R1) {
        u32 cum = excl; int bb = base;
        for (;; --bb) { cum += hist[bb]; if (cum >= R1) break; }
        sh_B2 = (u32)bb;
      }
    }
    __syncthreads();
    u32 B2 = sh_B2;
    for (int i = tid; i < A_TOTAL; i += STH) {
      u32 k = __float_as_uint(S[i]);
      if ((k >> 19) == B) {
        u32 sb = (k >> 7) & 0xFFFu;
        if (sb > B2) {
          u32 p = atomicAdd(&sh_cntA, 1u);
          if (p < 5120u) listA[p] = pack_key(k, (u32)i);
        } else if (sb == B2) {
          u32 p = atomicAdd(&sh_cntE, 1u);
          if (p < 2048u) listE[p] = pack_key(k, (u32)i);
        }
      }
    }
    __syncthreads();
    g = sh_cntA; if (g > 5120u) g = 5120u;
    h = sh_cntE; if (h > 2048u) h = 2048u;   // pathological exact-tie clamp (never on this data)
  }

  u32 R = KTOP - g;        // >= 1 since g <= 4999
  if (R > h) R = h;

  // ---- bitonic sort listE descending (padded to pow2) ----
  u32 P = 1; while (P < h) P <<= 1;
  for (u32 i = tid; i < P; i += STH) if (i >= h) listE[i] = 0ULL;
  __syncthreads();
  for (u32 kk = 2; kk <= P; kk <<= 1) {
    for (u32 jj = kk >> 1; jj > 0; jj >>= 1) {
      for (u32 i = tid; i < P; i += STH) {
        u32 ixj = i ^ jj;
        if (ixj > i) {
          u64 x = listE[i], y = listE[ixj];
          bool up = ((i & kk) == 0);
          if (up ? (x < y) : (x > y)) { listE[i] = y; listE[ixj] = x; }
        }
      }
      __syncthreads();
    }
  }

  // ---- load final 5000-set into registers (keys + boxes) ----
  u64 key[5]; float4 kbox[5];
  const u64 thrpack = ((u64)KTHR) << 32;
  u32 M = g + R;
  #pragma unroll
  for (int j = 0; j < 5; ++j) {
    u32 s = (u32)tid + (u32)j * STH;
    u64 kp = 0ULL;
    if (s < g) kp = listA[s];
    else if (s < M) kp = listE[s - g];
    if (kp < thrpack) kp = 0ULL;            // score >= 0.05 filter (incl. empty)
    key[j] = kp;
    if (kp) {
      u32 idx = 0xFFFFFFFFu - (u32)(kp & 0xFFFFFFFFull);
      kbox[j] = boxes4[(size_t)b * A_TOTAL + idx];
    } else {
      kbox[j] = make_float4(0.f, 0.f, 0.f, 0.f);
    }
  }

  // ---- greedy NMS: 100 x (register argmax + register IoU sweep) ----
  float* outS = nms_s + (size_t)lane_id * MAXT;
  float* outB = nms_b + (size_t)lane_id * MAXT * 4;
  int wid = tid >> 6, wlane = tid & 63;
  for (int pick = 0; pick < MAXT; ++pick) {
    u64 m = key[0];
    #pragma unroll
    for (int j = 1; j < 5; ++j) if (key[j] > m) m = key[j];
    #pragma unroll
    for (int off = 1; off < 64; off <<= 1) {
      u64 o = __shfl_xor(m, off);
      if (o > m) m = o;
    }
    if (wlane == 0) partial[wid] = m;
    __syncthreads();
    if (tid < 16) {
      u64 m2 = partial[tid];
      #pragma unroll
      for (int off = 1; off < 16; off <<= 1) {
        u64 o = __shfl_xor(m2, off);
        if (o > m2) m2 = o;
      }
      if (tid == 0) winsh = m2;
    }
    __syncthreads();
    u64 win = winsh;
    if (win == 0ULL) {                       // pool exhausted -> pad like reference
      for (int p = pick + tid; p < MAXT; p += STH) {
        outS[p] = -1.0f;
        *(float4*)(outB + p * 4) = make_float4(0.f, 0.f, 0.f, 0.f);
      }
      break;
    }
    u32 widx = 0xFFFFFFFFu - (u32)(win & 0xFFFFFFFFull);
    float4 pb = boxes4[(size_t)b * A_TOTAL + widx];   // uniform L2-hit load
    #pragma unroll
    for (int j = 0; j < 5; ++j) if (key[j] == win) key[j] = 0ULL;
    if (tid == 0) {
      outS[pick] = __uint_as_float((u32)(win >> 32));
      *(float4*)(outB + pick * 4) = pb;
    }
    float pa = (pb.z - pb.x) * (pb.w - pb.y);
    #pragma unroll
    for (int j = 0; j < 5; ++j) {
      if (key[j] != 0ULL) {
        float4 bb = kbox[j];
        float yy1 = fmaxf(pb.x, bb.x);
        float xx1 = fmaxf(pb.y, bb.y);
        float yy2 = fminf(pb.z, bb.z);
        float xx2 = fminf(pb.w, bb.w);
        float inter = fmaxf(yy2 - yy1, 0.0f) * fmaxf(xx2 - xx1, 0.0f);
        float aj = (bb.z - bb.x) * (bb.w - bb.y);
        float iou = inter / (pa + aj - inter + 1e-8f);
        if (iou > 0.3f) key[j] = 0ULL;
      }
    }
  }
}

// ---------------- final per-batch top-100: wave-synchronous 90-way merge ----------------
__global__ void merge_kernel(const float* __restrict__ nms_s, const float* __restrict__ nms_b,
                             float* __restrict__ out_b, float* __restrict__ out_s,
                             float* __restrict__ out_c, float* __restrict__ out_v)
{
  int b = blockIdx.x, lane = threadIdx.x;   // 64 threads = 1 wave
  __shared__ float ssc[NCLS * MAXT];        // 36 KB
  for (int i = lane; i < NCLS * MAXT; i += 64) ssc[i] = nms_s[(size_t)b * NCLS * MAXT + i];
  __syncthreads();
  int c0 = lane, c1 = lane + 64;
  int h0 = 0, h1 = 0;

  auto mkkey = [&](int c, int hh) -> u64 {
    if (c >= NCLS || hh >= MAXT) return 0ULL;
    float s = ssc[c * MAXT + hh];
    u32 u = __float_as_uint(s);
    u = (u & 0x80000000u) ? ~u : (u | 0x80000000u);
    u32 flat = (u32)(c * MAXT + hh);
    return ((u64)u << 32) | (u64)(0xFFFFFFFFu - flat);
  };
  u64 k0 = mkkey(c0, h0), k1 = mkkey(c1, h1);
  int vcnt = 0;
  for (int t = 0; t < MAXT; ++t) {
    u64 m = (k0 > k1) ? k0 : k1;
    #pragma unroll
    for (int off = 1; off < 64; off <<= 1) {
      u64 o = __shfl_xor(m, off);
      if (o > m) m = o;
    }
    u32 u = (u32)(m >> 32);
    u32 bits = (u & 0x80000000u) ? (u ^ 0x80000000u) : ~u;
    float s = __uint_as_float(bits);
    u32 flat = 0xFFFFFFFFu - (u32)(m & 0xFFFFFFFFull);
    int cls = (int)(flat / MAXT), pos = (int)(flat % MAXT);
    if (lane == 0) {
      out_s[b * MAXT + t] = s;
      out_c[b * MAXT + t] = (float)(cls + 1);
      *(float4*)(out_b + ((size_t)b * MAXT + t) * 4) =
          *(const float4*)(nms_b + (((size_t)b * NCLS + cls) * MAXT + pos) * 4);
      if (s > -1.0f) vcnt++;
    }
    if (cls == c0) { h0++; k0 = mkkey(c0, h0); }
    else if (cls == c1) { h1++; k1 = mkkey(c1, h1); }
  }
  if (lane == 0) out_v[b] = (float)vcnt;
}

extern "C" void kernel_launch(void* const* d_in, const int* in_sizes, int n_in,
                              void* d_out, int out_size, void* d_ws, size_t ws_size,
                              hipStream_t stream)
{
  const float* box[5]; const float* cls[5]; const float* anc[5];
  bool interleaved = (in_sizes[1] == 2 * 57600 * 91);   // setup_inputs dict order
  if (interleaved) {
    for (int l = 0; l < 5; ++l) {
      box[l] = (const float*)d_in[3 * l + 0];
      cls[l] = (const float*)d_in[3 * l + 1];
      anc[l] = (const float*)d_in[3 * l + 2];
    }
  } else {
    for (int l = 0; l < 5; ++l) {
      box[l] = (const float*)d_in[l];
      cls[l] = (const float*)d_in[5 + l];
      anc[l] = (const float*)d_in[10 + l];
    }
  }
  const float* img = (const float*)d_in[15];

  float* ws = (float*)d_ws;
  float* boxes_ws = ws;                    // 2*76725*4      = 613800 f
  float* scores_t = boxes_ws + 613800;     // 2*90*76725     = 13810500 f
  float* nms_s    = scores_t + 13810500;   // 180*100        = 18000 f
  float* nms_b    = nms_s + 18000;         // 180*100*4      = 72000 f

  decode_kernel<<<(2 * A_TOTAL + 255) / 256, 256, 0, stream>>>(
      box[0], box[1], box[2], box[3], box[4],
      anc[0], anc[1], anc[2], anc[3], anc[4], img, boxes_ws);

  transpose_kernel<<<2402, 256, 0, stream>>>(cls[0], cls[1], cls[2], cls[3], cls[4], scores_t);

  select_nms_kernel<<<180, STH, 0, stream>>>(scores_t, boxes_ws, nms_s, nms_b);

  float* out_b = (float*)d_out;  // [2][100][4]
  float* out_s = out_b + 800;    // [2][100]
  float* out_c = out_s + 200;    // [2][100]
  float* out_v = out_c + 200;    // [2]
  merge_kernel<<<2, 64, 0, stream>>>(nms_s, nms_b, out_b, out_s, out_c, out_v);
}

// Round 3
// 366.936 us; speedup vs baseline: 3.5753x; 1.0528x over previous
//
#include <hip/hip_runtime.h>
#include <hip/hip_bf16.h>

typedef unsigned long long u64;
typedef unsigned int u32;

#define A_TOTAL 76725
#define A_PAD   76736            /* padded to /4 for float4 loads */
#define QCH     (A_PAD / 4)      /* 19184 anchors per quarter-chunk */
#define NCLS 90
#define KTOP 5000u
#define MAXT 100
#define KTHR 0x3D4CCCCDu         /* bits of 0.05f */

__device__ __forceinline__ u64 pack_key(u32 k, u32 i) {
  return ((u64)k << 32) | (u64)(0xFFFFFFFFu - i);
}

// Parallel 2-level cutoff scan over a 4096-bucket histogram (call with full wave 0).
// Returns smallest bucket B such that sum(hist[b] for b > B) < need <= sum(b >= B).
__device__ __forceinline__ u32 scan_cut(const u32* gh, u32 need, int tid) {
  int base = 4095 - tid * 64;
  u32 s = 0;
  #pragma unroll
  for (int j = 0; j < 64; ++j) s += gh[base - j];
  u32 incl = s;
  #pragma unroll
  for (int off = 1; off < 64; off <<= 1) {
    u32 o = __shfl_up(incl, off, 64);
    if (tid >= off) incl += o;
  }
  u32 excl = incl - s;
  bool cross = (excl < need) && (incl >= need);
  u64 bal = __ballot(cross);
  int cl = __ffsll((unsigned long long)bal) - 1;
  int cbase = 4095 - cl * 64;
  u32 cexcl = __shfl(excl, cl, 64);
  u32 v = gh[cbase - tid];
  u32 incl2 = v;
  #pragma unroll
  for (int off = 1; off < 64; off <<= 1) {
    u32 o = __shfl_up(incl2, off, 64);
    if (tid >= off) incl2 += o;
  }
  bool c2 = (cexcl + incl2 >= need) && (cexcl + incl2 - v < need);
  u64 bal2 = __ballot(c2);
  int j2 = __ffsll((unsigned long long)bal2) - 1;
  return (u32)(cbase - j2);
}

// ---------------- decode + clip (+ zero hist/counters/pad) ----------------
__global__ __launch_bounds__(256) void decode_kernel(
    const float* __restrict__ bx0, const float* __restrict__ bx1, const float* __restrict__ bx2,
    const float* __restrict__ bx3, const float* __restrict__ bx4,
    const float* __restrict__ an0, const float* __restrict__ an1, const float* __restrict__ an2,
    const float* __restrict__ an3, const float* __restrict__ an4,
    const float* __restrict__ img, float* __restrict__ boxes,
    u32* __restrict__ zero_base, float* __restrict__ scores_t)
{
  int t = blockIdx.x * blockDim.x + threadIdx.x;
  int nth = gridDim.x * blockDim.x;
  // zero global hist (180*4096) + cntA/cntE/B (3*180)
  for (int i = t; i < 180 * 4096 + 540; i += nth) zero_base[i] = 0;
  // zero scores_t pad region
  if (t < 180 * (A_PAD - A_TOTAL)) {
    int lane = t / (A_PAD - A_TOTAL), off = t % (A_PAD - A_TOTAL);
    scores_t[(size_t)lane * A_PAD + A_TOTAL + off] = 0.0f;
  }
  if (t >= 2 * A_TOTAL) return;
  int b = t / A_TOTAL, a = t % A_TOTAL;
  const float* bp; const float* ap; int al; int nl;
  if (a < 57600)      { bp = bx0; ap = an0; al = a;          nl = 57600; }
  else if (a < 72000) { bp = bx1; ap = an1; al = a - 57600;  nl = 14400; }
  else if (a < 75600) { bp = bx2; ap = an2; al = a - 72000;  nl = 3600;  }
  else if (a < 76500) { bp = bx3; ap = an3; al = a - 75600;  nl = 900;   }
  else                { bp = bx4; ap = an4; al = a - 76500;  nl = 225;   }
  float4 e  = *(const float4*)(bp + ((size_t)b * nl + al) * 4);
  float4 an = *(const float4*)(ap + ((size_t)b * nl + al) * 4);
  const float CLIP = 4.135166556742356f; // log(1000/16)
  float ah  = an.z - an.x + 1.0f;
  float aw  = an.w - an.y + 1.0f;
  float ayc = an.x + 0.5f * ah;
  float axc = an.y + 0.5f * aw;
  float dh = fminf(e.z, CLIP), dw = fminf(e.w, CLIP);
  float yc = e.x * ah + ayc;
  float xc = e.y * aw + axc;
  float h  = expf(dh) * ah;
  float w  = expf(dw) * aw;
  float ymin = yc - 0.5f * h;
  float xmin = xc - 0.5f * w;
  float ymax = ymin + h - 1.0f;
  float xmax = xmin + w - 1.0f;
  float H = img[b * 2 + 0], W = img[b * 2 + 1];
  float4 o;
  o.x = fminf(fmaxf(ymin, 0.0f), H);
  o.y = fminf(fmaxf(xmin, 0.0f), W);
  o.z = fminf(fmaxf(ymax, 0.0f), H);
  o.w = fminf(fmaxf(xmax, 0.0f), W);
  *(float4*)(boxes + (size_t)t * 4) = o;
}

// ---------------- sigmoid + transpose to [B,90,A_PAD] ----------------
__global__ __launch_bounds__(256) void transpose_kernel(
    const float* __restrict__ c3, const float* __restrict__ c4, const float* __restrict__ c5,
    const float* __restrict__ c6, const float* __restrict__ c7, float* __restrict__ scores_t)
{
  __shared__ float lds[64 * 91];
  int blk = blockIdx.x;
  int lvl, local;
  if      (blk < 1800) { lvl = 0; local = blk; }
  else if (blk < 2250) { lvl = 1; local = blk - 1800; }
  else if (blk < 2364) { lvl = 2; local = blk - 2250; }
  else if (blk < 2394) { lvl = 3; local = blk - 2364; }
  else                 { lvl = 4; local = blk - 2394; }
  const int ns[5]    = {57600, 14400, 3600, 900, 225};
  const int bases[5] = {0, 57600, 72000, 75600, 76500};
  const int tl[5]    = {900, 225, 57, 15, 4};
  const float* cls = (lvl == 0) ? c3 : (lvl == 1) ? c4 : (lvl == 2) ? c5 : (lvl == 3) ? c6 : c7;
  int n = ns[lvl], base = bases[lvl], tiles = tl[lvl];
  int b = local / tiles, tile = local % tiles;
  int a0 = tile * 64;
  int cnt = n - a0; if (cnt > 64) cnt = 64;
  const float* src = cls + ((size_t)b * n + a0) * 91;
  int total = cnt * 91;
  for (int i = threadIdx.x; i < total; i += 256) lds[i] = src[i];
  __syncthreads();
  for (int j = threadIdx.x; j < NCLS * 64; j += 256) {
    int c = j >> 6, a = j & 63;
    if (a < cnt) {
      float x = lds[a * 91 + c + 1];
      scores_t[((size_t)(b * NCLS + c)) * A_PAD + base + a0 + a] = 1.0f / (1.0f + expf(-x));
    }
  }
}

// ---------------- per-lane global histograms (720 blocks = 4 per lane) ----------------
__global__ __launch_bounds__(512) void hist_kernel(const float* __restrict__ scores_t,
                                                   u32* __restrict__ hist_g)
{
  __shared__ u32 hist[4096];
  int tid = threadIdx.x;
  int lane = blockIdx.x >> 2, q = blockIdx.x & 3;
  for (int i = tid; i < 4096; i += 512) hist[i] = 0;
  __syncthreads();
  const float4* S4 = (const float4*)(scores_t + (size_t)lane * A_PAD + q * QCH);
  for (int i = tid; i < QCH / 4; i += 512) {
    float4 v = S4[i];
    atomicAdd(&hist[__float_as_uint(v.x) >> 19], 1u);
    atomicAdd(&hist[__float_as_uint(v.y) >> 19], 1u);
    atomicAdd(&hist[__float_as_uint(v.z) >> 19], 1u);
    atomicAdd(&hist[__float_as_uint(v.w) >> 19], 1u);
  }
  __syncthreads();
  u32* gh = hist_g + (size_t)lane * 4096;
  for (int i = tid; i < 4096; i += 512) {
    u32 v = hist[i];
    if (v) atomicAdd(&gh[i], v);
  }
}

// ---------------- collect candidates into per-lane global lists ----------------
__global__ __launch_bounds__(512) void collect_kernel(
    const float* __restrict__ scores_t, const u32* __restrict__ hist_g,
    u64* __restrict__ listA_g, u64* __restrict__ listE_g,
    u32* __restrict__ cntA_g, u32* __restrict__ cntE_g, u32* __restrict__ B_g)
{
  __shared__ u64 bufA[5120];    // 40 KB
  __shared__ u64 bufE[2048];    // 16 KB
  __shared__ u32 sh_B, sh_cA, sh_cE, sh_baseA, sh_baseE;
  int tid = threadIdx.x;
  int lane = blockIdx.x >> 2, q = blockIdx.x & 3;
  const u32* gh = hist_g + (size_t)lane * 4096;
  if (tid < 64) {
    u32 B = scan_cut(gh, KTOP, tid);
    if (tid == 0) { sh_B = B; sh_cA = 0; sh_cE = 0; }
  }
  __syncthreads();
  u32 B = sh_B;
  if (tid == 0 && q == 0) B_g[lane] = B;
  const float4* S4 = (const float4*)(scores_t + (size_t)lane * A_PAD + q * QCH);
  int base_idx = q * QCH;
  for (int i = tid; i < QCH / 4; i += 512) {
    float4 v = S4[i];
    u32 ks[4] = {__float_as_uint(v.x), __float_as_uint(v.y), __float_as_uint(v.z), __float_as_uint(v.w)};
    #pragma unroll
    for (int j = 0; j < 4; ++j) {
      u32 k = ks[j], bkt = k >> 19;
      u32 idx = (u32)(base_idx + i * 4 + j);
      if (bkt > B) {
        u32 p = atomicAdd(&sh_cA, 1u);
        if (p < 5120u) bufA[p] = pack_key(k, idx);
      } else if (bkt == B) {
        u32 p = atomicAdd(&sh_cE, 1u);
        if (p < 2048u) bufE[p] = pack_key(k, idx);
      }
    }
  }
  __syncthreads();
  u32 cA = sh_cA; if (cA > 5120u) cA = 5120u;
  u32 cE = sh_cE; if (cE > 2048u) cE = 2048u;
  if (tid == 0) {
    sh_baseA = atomicAdd(&cntA_g[lane], sh_cA);
    sh_baseE = atomicAdd(&cntE_g[lane], sh_cE);
  }
  __syncthreads();
  u32 bA = sh_baseA, bE = sh_baseE;
  u64* LA = listA_g + (size_t)lane * 5120;
  u64* LE = listE_g + (size_t)lane * 2048;
  for (u32 i = tid; i < cA; i += 512) { u32 d = bA + i; if (d < 5120u) LA[d] = bufA[i]; }
  for (u32 i = tid; i < cE; i += 512) { u32 d = bE + i; if (d < 2048u) LE[d] = bufE[i]; }
}

// ---------------- per-lane greedy NMS (register-resident, 1 barrier/pick) ----------------
__global__ __launch_bounds__(1024) void nms_kernel(
    const float* __restrict__ scores_t, const float* __restrict__ boxes,
    const u64* __restrict__ listA_g, const u64* __restrict__ listE_g,
    const u32* __restrict__ cntA_g, const u32* __restrict__ cntE_g, const u32* __restrict__ B_g,
    float* __restrict__ nms_s, float* __restrict__ nms_b)
{
  __shared__ __align__(16) char ebuf[16384];   // union: u64 listE[2048] / u32 hist[4096]
  __shared__ u64 slots[MAXT];
  __shared__ u32 sh_c0, sh_c1, sh_B2;
  u64* listE = (u64*)ebuf;
  u32* hist  = (u32*)ebuf;

  int tid = threadIdx.x;
  int lane = blockIdx.x;
  int b = lane / NCLS;
  const float4* boxes4 = (const float4*)boxes;

  u32 g = cntA_g[lane];
  u32 h = cntE_g[lane];
  u32 B = B_g[lane];
  u64* LAm = (u64*)listA_g + (size_t)lane * 5120;   // mutable view for rare refine append

  for (int i = tid; i < MAXT; i += 1024) slots[i] = 0ULL;

  if (h > 2048u) {
    // rare path: boundary bucket overflowed global listE -> refine on bits [18:7] from scores_t
    const float* S = scores_t + (size_t)lane * A_PAD;
    for (int i = tid; i < 4096; i += 1024) hist[i] = 0;
    if (tid == 0) { sh_c0 = 0; sh_c1 = 0; }
    __syncthreads();
    for (int i = tid; i < A_PAD; i += 1024) {
      u32 k = __float_as_uint(S[i]);
      if ((k >> 19) == B) atomicAdd(&hist[(k >> 7) & 0xFFFu], 1u);
    }
    __syncthreads();
    u32 R1 = KTOP - g;
    if (tid < 64) {
      u32 B2 = scan_cut(hist, R1, tid);
      if (tid == 0) sh_B2 = B2;
    }
    __syncthreads();
    u32 B2 = sh_B2;
    __syncthreads();   // all hist reads done before listE overwrites the same LDS
    for (int i = tid; i < A_PAD; i += 1024) {
      u32 k = __float_as_uint(S[i]);
      if ((k >> 19) == B) {
        u32 sb = (k >> 7) & 0xFFFu;
        if (sb > B2) {
          u32 p = atomicAdd(&sh_c0, 1u);
          if (g + p < 5120u) LAm[g + p] = pack_key(k, (u32)i);
        } else if (sb == B2) {
          u32 p = atomicAdd(&sh_c1, 1u);
          if (p < 2048u) listE[p] = pack_key(k, (u32)i);
        }
      }
    }
    __syncthreads();
    g += sh_c0; if (g > 5120u) g = 5120u;
    h = sh_c1;  if (h > 2048u) h = 2048u;
  } else {
    const u64* LE = listE_g + (size_t)lane * 2048;
    for (u32 i = tid; i < h; i += 1024) listE[i] = LE[i];
  }

  u32 R = KTOP - g; if (R > h) R = h;

  // bitonic sort listE descending (padded to pow2)
  u32 P = 1; while (P < h) P <<= 1;
  for (u32 i = tid; i < P; i += 1024) if (i >= h) listE[i] = 0ULL;
  __syncthreads();
  for (u32 kk = 2; kk <= P; kk <<= 1) {
    for (u32 jj = kk >> 1; jj > 0; jj >>= 1) {
      for (u32 i = tid; i < P; i += 1024) {
        u32 ixj = i ^ jj;
        if (ixj > i) {
          u64 x = listE[i], y = listE[ixj];
          bool up = ((i & kk) == 0);
          if (up ? (x < y) : (x > y)) { listE[i] = y; listE[ixj] = x; }
        }
      }
      __syncthreads();
    }
  }

  // load final 5000-set into registers (keys + boxes)
  u64 key[5]; float4 kbox[5];
  const u64 thrpack = ((u64)KTHR) << 32;
  u32 M = g + R;
  #pragma unroll
  for (int j = 0; j < 5; ++j) {
    u32 s = (u32)tid + (u32)j * 1024u;
    u64 kp = 0ULL;
    if (s < g) kp = LAm[s];
    else if (s < M) kp = listE[s - g];
    if (kp < thrpack) kp = 0ULL;            // score >= 0.05 filter (incl. empty)
    key[j] = kp;
    if (kp) {
      u32 idx = 0xFFFFFFFFu - (u32)(kp & 0xFFFFFFFFull);
      kbox[j] = boxes4[(size_t)b * A_TOTAL + idx];
    } else {
      kbox[j] = make_float4(0.f, 0.f, 0.f, 0.f);
    }
  }
  __syncthreads();

  // greedy NMS: 100 x (register argmax -> wave reduce -> LDS atomicMax slot, 1 barrier)
  float* outS = nms_s + (size_t)lane * MAXT;
  float* outB = nms_b + (size_t)lane * MAXT * 4;
  for (int pick = 0; pick < MAXT; ++pick) {
    u64 m = key[0];
    #pragma unroll
    for (int j = 1; j < 5; ++j) if (key[j] > m) m = key[j];
    #pragma unroll
    for (int off = 1; off < 64; off <<= 1) {
      u64 o = __shfl_xor(m, off);
      if (o > m) m = o;
    }
    if ((tid & 63) == 0 && m != 0ULL) atomicMax((unsigned long long*)&slots[pick], m);
    __syncthreads();
    u64 win = slots[pick];
    if (win == 0ULL) {                       // pool exhausted -> pad like reference
      for (int p = pick + tid; p < MAXT; p += 1024) {
        outS[p] = -1.0f;
        *(float4*)(outB + p * 4) = make_float4(0.f, 0.f, 0.f, 0.f);
      }
      break;
    }
    u32 widx = 0xFFFFFFFFu - (u32)(win & 0xFFFFFFFFull);
    float4 pb = boxes4[(size_t)b * A_TOTAL + widx];   // uniform L2-hit load
    #pragma unroll
    for (int j = 0; j < 5; ++j) if (key[j] == win) key[j] = 0ULL;
    if (tid == 0) {
      outS[pick] = __uint_as_float((u32)(win >> 32));
      *(float4*)(outB + pick * 4) = pb;
    }
    float pa = (pb.z - pb.x) * (pb.w - pb.y);
    #pragma unroll
    for (int j = 0; j < 5; ++j) {
      if (key[j] != 0ULL) {
        float4 bb = kbox[j];
        float yy1 = fmaxf(pb.x, bb.x);
        float xx1 = fmaxf(pb.y, bb.y);
        float yy2 = fminf(pb.z, bb.z);
        float xx2 = fminf(pb.w, bb.w);
        float inter = fmaxf(yy2 - yy1, 0.0f) * fmaxf(xx2 - xx1, 0.0f);
        float aj = (bb.z - bb.x) * (bb.w - bb.y);
        float iou = inter / (pa + aj - inter + 1e-8f);
        if (iou > 0.3f) key[j] = 0ULL;
      }
    }
  }
}

// ---------------- final per-batch top-100: 90-way merge, 1 barrier/iter ----------------
__global__ __launch_bounds__(128) void merge_kernel(
    const float* __restrict__ nms_s, const float* __restrict__ nms_b,
    float* __restrict__ out_b, float* __restrict__ out_s,
    float* __restrict__ out_c, float* __restrict__ out_v)
{
  int b = blockIdx.x, tid = threadIdx.x;   // 128 threads = 2 waves
  __shared__ float ssc[NCLS * MAXT];
  __shared__ u64 slots[MAXT];
  for (int i = tid; i < NCLS * MAXT; i += 128) ssc[i] = nms_s[(size_t)b * NCLS * MAXT + i];
  for (int i = tid; i < MAXT; i += 128) slots[i] = 0ULL;
  int c = tid, hh = 0;
  auto mkkey = [&](int cc, int hx) -> u64 {
    if (cc >= NCLS || hx >= MAXT) return 0ULL;
    float s = ssc[cc * MAXT + hx];
    u32 u = __float_as_uint(s);
    u = (u & 0x80000000u) ? ~u : (u | 0x80000000u);
    u32 flat = (u32)(cc * MAXT + hx);
    return ((u64)u << 32) | (u64)(0xFFFFFFFFu - flat);
  };
  __syncthreads();
  u64 k = mkkey(c, hh);
  int vcnt = 0;
  for (int t = 0; t < MAXT; ++t) {
    u64 m = k;
    #pragma unroll
    for (int off = 1; off < 64; off <<= 1) {
      u64 o = __shfl_xor(m, off);
      if (o > m) m = o;
    }
    if ((tid & 63) == 0 && m != 0ULL) atomicMax((unsigned long long*)&slots[t], m);
    __syncthreads();
    u64 win = slots[t];
    u32 u = (u32)(win >> 32);
    u32 bits = (u & 0x80000000u) ? (u ^ 0x80000000u) : ~u;
    float s = __uint_as_float(bits);
    u32 flat = 0xFFFFFFFFu - (u32)(win & 0xFFFFFFFFull);
    int cls = (int)(flat / MAXT), pos = (int)(flat % MAXT);
    if (tid == 0) {
      out_s[b * MAXT + t] = s;
      out_c[b * MAXT + t] = (float)(cls + 1);
      *(float4*)(out_b + ((size_t)b * MAXT + t) * 4) =
          *(const float4*)(nms_b + (((size_t)b * NCLS + cls) * MAXT + pos) * 4);
      if (s > -1.0f) vcnt++;
    }
    if (c == cls) { hh++; k = mkkey(c, hh); }
  }
  if (tid == 0) out_v[b] = (float)vcnt;
}

extern "C" void kernel_launch(void* const* d_in, const int* in_sizes, int n_in,
                              void* d_out, int out_size, void* d_ws, size_t ws_size,
                              hipStream_t stream)
{
  const float* box[5]; const float* cls[5]; const float* anc[5];
  bool interleaved = (in_sizes[1] == 2 * 57600 * 91);   // setup_inputs dict order
  if (interleaved) {
    for (int l = 0; l < 5; ++l) {
      box[l] = (const float*)d_in[3 * l + 0];
      cls[l] = (const float*)d_in[3 * l + 1];
      anc[l] = (const float*)d_in[3 * l + 2];
    }
  } else {
    for (int l = 0; l < 5; ++l) {
      box[l] = (const float*)d_in[l];
      cls[l] = (const float*)d_in[5 + l];
      anc[l] = (const float*)d_in[10 + l];
    }
  }
  const float* img = (const float*)d_in[15];

  float* ws = (float*)d_ws;
  float* boxes_ws = ws;                          // 613800 f
  float* scores_t = boxes_ws + 613800;           // 180*76736       = 13812480 f
  u32*   hist_g   = (u32*)(scores_t + 13812480); // 180*4096        = 737280 u32
  u32*   cntA_g   = hist_g + 737280;             // 180
  u32*   cntE_g   = cntA_g + 180;                // 180
  u32*   B_g      = cntE_g + 180;                // 180
  u64*   listA_g  = (u64*)(B_g + 180);           // 180*5120 u64
  u64*   listE_g  = listA_g + 180 * 5120;        // 180*2048 u64
  float* nms_s    = (float*)(listE_g + 180 * 2048);  // 18000 f
  float* nms_b    = nms_s + 18000;               // 72000 f

  decode_kernel<<<600, 256, 0, stream>>>(
      box[0], box[1], box[2], box[3], box[4],
      anc[0], anc[1], anc[2], anc[3], anc[4], img, boxes_ws, hist_g, scores_t);

  transpose_kernel<<<2402, 256, 0, stream>>>(cls[0], cls[1], cls[2], cls[3], cls[4], scores_t);

  hist_kernel<<<720, 512, 0, stream>>>(scores_t, hist_g);

  collect_kernel<<<720, 512, 0, stream>>>(scores_t, hist_g, listA_g, listE_g,
                                          cntA_g, cntE_g, B_g);

  nms_kernel<<<180, 1024, 0, stream>>>(scores_t, boxes_ws, listA_g, listE_g,
                                       cntA_g, cntE_g, B_g, nms_s, nms_b);

  float* out_b = (float*)d_out;  // [2][100][4]
  float* out_s = out_b + 800;    // [2][100]
  float* out_c = out_s + 200;    // [2][100]
  float* out_v = out_c + 200;    // [2]
  merge_kernel<<<2, 128, 0, stream>>>(nms_s, nms_b, out_b, out_s, out_c, out_v);
}

// Round 4
// 241.605 us; speedup vs baseline: 5.4299x; 1.5187x over previous
//
#include <hip/hip_runtime.h>
#include <hip/hip_bf16.h>

typedef unsigned long long u64;
typedef unsigned int u32;

#define A_TOTAL 76725
#define A_PAD   76736            /* padded to /4 for float4 loads */
#define QCH     (A_PAD / 4)      /* 19184 anchors per quarter-chunk */
#define NCLS 90
#define KTOP 5000u
#define MAXT 100
#define MAXC 3072                /* sorted top-chunk capacity */
#define KTHR 0x3D4CCCCDu         /* bits of 0.05f */

__device__ __forceinline__ u64 pack_key(u32 k, u32 i) {
  return ((u64)k << 32) | (u64)(0xFFFFFFFFu - i);
}

// Parallel 2-level cutoff scan over a 4096-bucket histogram (call with full wave 0).
// Returns smallest bucket B such that sum(hist[b] for b > B) < need <= sum(b >= B).
__device__ __forceinline__ u32 scan_cut(const u32* gh, u32 need, int tid) {
  int base = 4095 - tid * 64;
  u32 s = 0;
  #pragma unroll
  for (int j = 0; j < 64; ++j) s += gh[base - j];
  u32 incl = s;
  #pragma unroll
  for (int off = 1; off < 64; off <<= 1) {
    u32 o = __shfl_up(incl, off, 64);
    if (tid >= off) incl += o;
  }
  u32 excl = incl - s;
  bool cross = (excl < need) && (incl >= need);
  u64 bal = __ballot(cross);
  int cl = __ffsll((unsigned long long)bal) - 1;
  int cbase = 4095 - cl * 64;
  u32 cexcl = __shfl(excl, cl, 64);
  u32 v = gh[cbase - tid];
  u32 incl2 = v;
  #pragma unroll
  for (int off = 1; off < 64; off <<= 1) {
    u32 o = __shfl_up(incl2, off, 64);
    if (tid >= off) incl2 += o;
  }
  bool c2 = (cexcl + incl2 >= need) && (cexcl + incl2 - v < need);
  u64 bal2 = __ballot(c2);
  int j2 = __ffsll((unsigned long long)bal2) - 1;
  return (u32)(cbase - j2);
}

// Same, but also returns cnt = count of elements in buckets >= B (uniform in wave).
__device__ __forceinline__ void scan_cut2(const u32* gh, u32 need, int tid,
                                          u32* outB, u32* outCnt) {
  int base = 4095 - tid * 64;
  u32 s = 0;
  #pragma unroll
  for (int j = 0; j < 64; ++j) s += gh[base - j];
  u32 incl = s;
  #pragma unroll
  for (int off = 1; off < 64; off <<= 1) {
    u32 o = __shfl_up(incl, off, 64);
    if (tid >= off) incl += o;
  }
  u32 excl = incl - s;
  bool cross = (excl < need) && (incl >= need);
  u64 bal = __ballot(cross);
  int cl = __ffsll((unsigned long long)bal) - 1;
  int cbase = 4095 - cl * 64;
  u32 cexcl = __shfl(excl, cl, 64);
  u32 v = gh[cbase - tid];
  u32 incl2 = v;
  #pragma unroll
  for (int off = 1; off < 64; off <<= 1) {
    u32 o = __shfl_up(incl2, off, 64);
    if (tid >= off) incl2 += o;
  }
  bool c2 = (cexcl + incl2 >= need) && (cexcl + incl2 - v < need);
  u64 bal2 = __ballot(c2);
  int j2 = __ffsll((unsigned long long)bal2) - 1;
  *outB = (u32)(cbase - j2);
  *outCnt = cexcl + __shfl(incl2, j2, 64);
}

// Block-cooperative descending bitonic sort of a[0..n) padded to pow2 with 0.
__device__ __forceinline__ void bitonic_desc(u64* a, u32 n, int tid, int nth) {
  u32 P = 2; while (P < n) P <<= 1;
  for (u32 i = tid; i < P; i += nth) if (i >= n) a[i] = 0ULL;
  __syncthreads();
  for (u32 kk = 2; kk <= P; kk <<= 1) {
    for (u32 jj = kk >> 1; jj; jj >>= 1) {
      for (u32 i = tid; i < P; i += nth) {
        u32 ixj = i ^ jj;
        if (ixj > i) {
          u64 x = a[i], y = a[ixj];
          bool up = ((i & kk) == 0);
          if (up ? (x < y) : (x > y)) { a[i] = y; a[ixj] = x; }
        }
      }
      __syncthreads();
    }
  }
}

// ---------------- decode + clip (+ zero hist/counters/pad) ----------------
__global__ __launch_bounds__(256) void decode_kernel(
    const float* __restrict__ bx0, const float* __restrict__ bx1, const float* __restrict__ bx2,
    const float* __restrict__ bx3, const float* __restrict__ bx4,
    const float* __restrict__ an0, const float* __restrict__ an1, const float* __restrict__ an2,
    const float* __restrict__ an3, const float* __restrict__ an4,
    const float* __restrict__ img, float* __restrict__ boxes,
    u32* __restrict__ zero_base, float* __restrict__ scores_t)
{
  int t = blockIdx.x * blockDim.x + threadIdx.x;
  int nth = gridDim.x * blockDim.x;
  for (int i = t; i < 180 * 4096 + 540; i += nth) zero_base[i] = 0;
  if (t < 180 * (A_PAD - A_TOTAL)) {
    int lane = t / (A_PAD - A_TOTAL), off = t % (A_PAD - A_TOTAL);
    scores_t[(size_t)lane * A_PAD + A_TOTAL + off] = 0.0f;
  }
  if (t >= 2 * A_TOTAL) return;
  int b = t / A_TOTAL, a = t % A_TOTAL;
  const float* bp; const float* ap; int al; int nl;
  if (a < 57600)      { bp = bx0; ap = an0; al = a;          nl = 57600; }
  else if (a < 72000) { bp = bx1; ap = an1; al = a - 57600;  nl = 14400; }
  else if (a < 75600) { bp = bx2; ap = an2; al = a - 72000;  nl = 3600;  }
  else if (a < 76500) { bp = bx3; ap = an3; al = a - 75600;  nl = 900;   }
  else                { bp = bx4; ap = an4; al = a - 76500;  nl = 225;   }
  float4 e  = *(const float4*)(bp + ((size_t)b * nl + al) * 4);
  float4 an = *(const float4*)(ap + ((size_t)b * nl + al) * 4);
  const float CLIP = 4.135166556742356f; // log(1000/16)
  float ah  = an.z - an.x + 1.0f;
  float aw  = an.w - an.y + 1.0f;
  float ayc = an.x + 0.5f * ah;
  float axc = an.y + 0.5f * aw;
  float dh = fminf(e.z, CLIP), dw = fminf(e.w, CLIP);
  float yc = e.x * ah + ayc;
  float xc = e.y * aw + axc;
  float h  = expf(dh) * ah;
  float w  = expf(dw) * aw;
  float ymin = yc - 0.5f * h;
  float xmin = xc - 0.5f * w;
  float ymax = ymin + h - 1.0f;
  float xmax = xmin + w - 1.0f;
  float H = img[b * 2 + 0], W = img[b * 2 + 1];
  float4 o;
  o.x = fminf(fmaxf(ymin, 0.0f), H);
  o.y = fminf(fmaxf(xmin, 0.0f), W);
  o.z = fminf(fmaxf(ymax, 0.0f), H);
  o.w = fminf(fmaxf(xmax, 0.0f), W);
  *(float4*)(boxes + (size_t)t * 4) = o;
}

// ---------------- sigmoid + transpose to [B,90,A_PAD] ----------------
__global__ __launch_bounds__(256) void transpose_kernel(
    const float* __restrict__ c3, const float* __restrict__ c4, const float* __restrict__ c5,
    const float* __restrict__ c6, const float* __restrict__ c7, float* __restrict__ scores_t)
{
  __shared__ float lds[64 * 91];
  int blk = blockIdx.x;
  int lvl, local;
  if      (blk < 1800) { lvl = 0; local = blk; }
  else if (blk < 2250) { lvl = 1; local = blk - 1800; }
  else if (blk < 2364) { lvl = 2; local = blk - 2250; }
  else if (blk < 2394) { lvl = 3; local = blk - 2364; }
  else                 { lvl = 4; local = blk - 2394; }
  const int ns[5]    = {57600, 14400, 3600, 900, 225};
  const int bases[5] = {0, 57600, 72000, 75600, 76500};
  const int tl[5]    = {900, 225, 57, 15, 4};
  const float* cls = (lvl == 0) ? c3 : (lvl == 1) ? c4 : (lvl == 2) ? c5 : (lvl == 3) ? c6 : c7;
  int n = ns[lvl], base = bases[lvl], tiles = tl[lvl];
  int b = local / tiles, tile = local % tiles;
  int a0 = tile * 64;
  int cnt = n - a0; if (cnt > 64) cnt = 64;
  const float* src = cls + ((size_t)b * n + a0) * 91;
  int total = cnt * 91;
  for (int i = threadIdx.x; i < total; i += 256) lds[i] = src[i];
  __syncthreads();
  for (int j = threadIdx.x; j < NCLS * 64; j += 256) {
    int c = j >> 6, a = j & 63;
    if (a < cnt) {
      float x = lds[a * 91 + c + 1];
      scores_t[((size_t)(b * NCLS + c)) * A_PAD + base + a0 + a] = 1.0f / (1.0f + expf(-x));
    }
  }
}

// ---------------- per-lane global histograms (720 blocks = 4 per lane) ----------------
__global__ __launch_bounds__(512) void hist_kernel(const float* __restrict__ scores_t,
                                                   u32* __restrict__ hist_g)
{
  __shared__ u32 hist[4096];
  int tid = threadIdx.x;
  int lane = blockIdx.x >> 2, q = blockIdx.x & 3;
  for (int i = tid; i < 4096; i += 512) hist[i] = 0;
  __syncthreads();
  const float4* S4 = (const float4*)(scores_t + (size_t)lane * A_PAD + q * QCH);
  for (int i = tid; i < QCH / 4; i += 512) {
    float4 v = S4[i];
    atomicAdd(&hist[__float_as_uint(v.x) >> 19], 1u);
    atomicAdd(&hist[__float_as_uint(v.y) >> 19], 1u);
    atomicAdd(&hist[__float_as_uint(v.z) >> 19], 1u);
    atomicAdd(&hist[__float_as_uint(v.w) >> 19], 1u);
  }
  __syncthreads();
  u32* gh = hist_g + (size_t)lane * 4096;
  for (int i = tid; i < 4096; i += 512) {
    u32 v = hist[i];
    if (v) atomicAdd(&gh[i], v);
  }
}

// ---------------- collect candidates into per-lane global lists ----------------
__global__ __launch_bounds__(512) void collect_kernel(
    const float* __restrict__ scores_t, const u32* __restrict__ hist_g,
    u64* __restrict__ listA_g, u64* __restrict__ listE_g,
    u32* __restrict__ cntA_g, u32* __restrict__ cntE_g, u32* __restrict__ B_g)
{
  __shared__ u64 bufA[5120];    // 40 KB
  __shared__ u64 bufE[2048];    // 16 KB
  __shared__ u32 sh_B, sh_cA, sh_cE, sh_baseA, sh_baseE;
  int tid = threadIdx.x;
  int lane = blockIdx.x >> 2, q = blockIdx.x & 3;
  const u32* gh = hist_g + (size_t)lane * 4096;
  if (tid < 64) {
    u32 B = scan_cut(gh, KTOP, tid);
    if (tid == 0) { sh_B = B; sh_cA = 0; sh_cE = 0; }
  }
  __syncthreads();
  u32 B = sh_B;
  if (tid == 0 && q == 0) B_g[lane] = B;
  const float4* S4 = (const float4*)(scores_t + (size_t)lane * A_PAD + q * QCH);
  int base_idx = q * QCH;
  for (int i = tid; i < QCH / 4; i += 512) {
    float4 v = S4[i];
    u32 ks[4] = {__float_as_uint(v.x), __float_as_uint(v.y), __float_as_uint(v.z), __float_as_uint(v.w)};
    #pragma unroll
    for (int j = 0; j < 4; ++j) {
      u32 k = ks[j], bkt = k >> 19;
      u32 idx = (u32)(base_idx + i * 4 + j);
      if (bkt > B) {
        u32 p = atomicAdd(&sh_cA, 1u);
        if (p < 5120u) bufA[p] = pack_key(k, idx);
      } else if (bkt == B) {
        u32 p = atomicAdd(&sh_cE, 1u);
        if (p < 2048u) bufE[p] = pack_key(k, idx);
      }
    }
  }
  __syncthreads();
  u32 cA = sh_cA; if (cA > 5120u) cA = 5120u;
  u32 cE = sh_cE; if (cE > 2048u) cE = 2048u;
  if (tid == 0) {
    sh_baseA = atomicAdd(&cntA_g[lane], sh_cA);
    sh_baseE = atomicAdd(&cntE_g[lane], sh_cE);
  }
  __syncthreads();
  u32 bA = sh_baseA, bE = sh_baseE;
  u64* LA = listA_g + (size_t)lane * 5120;
  u64* LE = listE_g + (size_t)lane * 2048;
  for (u32 i = tid; i < cA; i += 512) { u32 d = bA + i; if (d < 5120u) LA[d] = bufA[i]; }
  for (u32 i = tid; i < cE; i += 512) { u32 d = bE + i; if (d < 2048u) LE[d] = bufE[i]; }
}

// ---------------- per-lane greedy NMS: sorted top-chunk + ballot first-alive ----------------
__global__ __launch_bounds__(1024) void nms_kernel(
    const float* __restrict__ scores_t, const float* __restrict__ boxes,
    u64* __restrict__ listA_g, const u64* __restrict__ listE_g,
    const u32* __restrict__ cntA_g, const u32* __restrict__ cntE_g,
    const u32* __restrict__ B_g, const u32* __restrict__ hist_g,
    float* __restrict__ nms_s, float* __restrict__ nms_b)
{
  __shared__ __align__(16) char ebuf[16384];     // union: u64 listE[2048] / u32 hist2[4096]
  __shared__ u64 key_s[MAXC];                    // 24 KB sorted chunk keys
  __shared__ __align__(16) float4 box_s[MAXC];   // 48 KB chunk boxes; phase2: u64 pool_k[5120]
  __shared__ float4 wbox[MAXT];
  __shared__ u32 slots[MAXT];
  __shared__ u64 slots64[MAXT];
  __shared__ u32 sh_c0, sh_c1, sh_B2, sh_B1k, sh_cC, sh_Np;

  u64* listE  = (u64*)ebuf;
  u32* hist2  = (u32*)ebuf;
  u64* pool_k = (u64*)box_s;

  int tid = threadIdx.x;
  int lane = blockIdx.x;
  int b = lane / NCLS;
  const float4* boxes4 = (const float4*)boxes;
  size_t bbase = (size_t)b * A_TOTAL;
  const u64 thrpack = ((u64)KTHR) << 32;

  u32 g = cntA_g[lane];
  u32 h = cntE_g[lane];
  u32 B = B_g[lane];
  const u32* gh = hist_g + (size_t)lane * 4096;
  u64* LAm = listA_g + (size_t)lane * 5120;
  const u64* LEg = listE_g + (size_t)lane * 2048;

  for (int i = tid; i < MAXT; i += 1024) { slots[i] = 0xFFFFFFFFu; slots64[i] = 0ULL; }

  bool refined = false;
  bool sortedE = false;

  // ---- rare: global listE overflowed -> refine boundary on bits [18:7] ----
  if (h > 2048u) {
    const float* S = scores_t + (size_t)lane * A_PAD;
    for (int i = tid; i < 4096; i += 1024) hist2[i] = 0;
    if (tid == 0) { sh_c0 = 0; sh_c1 = 0; }
    __syncthreads();
    for (int i = tid; i < A_PAD; i += 1024) {
      u32 k = __float_as_uint(S[i]);
      if ((k >> 19) == B) atomicAdd(&hist2[(k >> 7) & 0xFFFu], 1u);
    }
    __syncthreads();
    u32 R1 = KTOP - g;
    if (tid < 64) {
      u32 B2 = scan_cut(hist2, R1, tid);
      if (tid == 0) sh_B2 = B2;
    }
    __syncthreads();
    u32 B2 = sh_B2;
    __syncthreads();   // all hist2 reads done before listE overwrites the same LDS
    for (int i = tid; i < A_PAD; i += 1024) {
      u32 k = __float_as_uint(S[i]);
      if ((k >> 19) == B) {
        u32 sb = (k >> 7) & 0xFFFu;
        if (sb > B2) {
          u32 p = atomicAdd(&sh_c0, 1u);
          if (g + p < 5120u) LAm[g + p] = pack_key(k, (u32)i);
        } else if (sb == B2) {
          u32 p = atomicAdd(&sh_c1, 1u);
          if (p < 2048u) listE[p] = pack_key(k, (u32)i);
        }
      }
    }
    __syncthreads();
    g += sh_c0; if (g > 5120u) g = 5120u;
    h = sh_c1;  if (h > 2048u) h = 2048u;
    refined = true;
  }

  u32 R = (g < KTOP) ? (KTOP - g) : 0;
  if (R > h) R = h;

  // ---- chunk threshold: bucket cut at rank ~1024, capped to MAXC raw ----
  if (tid < 64) {
    u32 B1k, cnt;
    scan_cut2(gh, 1024u, tid, &B1k, &cnt);
    if (tid == 0) {
      if (B1k > B) {
        while (cnt > (u32)MAXC && B1k < 4096u) { cnt -= gh[B1k]; B1k++; }
      }
      sh_B1k = B1k; sh_cC = 0; sh_Np = 0;
    }
  }
  __syncthreads();
  u32 B1k = sh_B1k;
  bool chunkEmpty = (B1k == B && g > (u32)MAXC);   // ultra-rare pathological

  // ---- build chunk ----
  u32 takeE = 0;
  if (B1k == B && !chunkEmpty) {
    if (!refined) {
      for (u32 i = tid; i < h; i += 1024) listE[i] = LEg[i];
    }
    bitonic_desc(listE, h, tid, 1024);
    sortedE = true;
    u32 capLeft = (u32)MAXC - g;
    takeE = (R < capLeft) ? R : capLeft;
  }
  __syncthreads();
  if (!chunkEmpty) {
    for (u32 s = tid; s < g; s += 1024) {
      u64 kp = LAm[s];
      if (kp >= thrpack && (u32)(kp >> 51) >= B1k) {
        u32 p = atomicAdd(&sh_cC, 1u);
        if (p < (u32)MAXC) key_s[p] = kp;
      }
    }
    for (u32 j = tid; j < takeE; j += 1024) {
      u64 kp = listE[j];
      if (kp >= thrpack) {
        u32 p = atomicAdd(&sh_cC, 1u);
        if (p < (u32)MAXC) key_s[p] = kp;
      }
    }
  }
  __syncthreads();
  u32 C = sh_cC; if (C > (u32)MAXC) C = MAXC;

  bitonic_desc(key_s, C, tid, 1024);

  for (u32 p = tid; p < C; p += 1024) {
    u32 idx = 0xFFFFFFFFu - (u32)(key_s[p] & 0xFFFFFFFFull);
    box_s[p] = boxes4[bbase + idx];
  }
  __syncthreads();

  // per-thread contiguous ownership: positions 3*tid .. 3*tid+2
  u64 mk0 = 0, mk1 = 0, mk2 = 0;
  float4 mb0, mb1, mb2;
  u32 p0 = 3u * (u32)tid;
  if (p0 < C)     { mk0 = key_s[p0];     mb0 = box_s[p0]; }
  if (p0 + 1 < C) { mk1 = key_s[p0 + 1]; mb1 = box_s[p0 + 1]; }
  if (p0 + 2 < C) { mk2 = key_s[p0 + 2]; mb2 = box_s[p0 + 2]; }

  float* outS = nms_s + (size_t)lane * MAXT;
  float* outB = nms_b + (size_t)lane * MAXT * 4;

  // ---- phase 1: picks from sorted chunk (1 barrier/pick) ----
  int donepicks = MAXT;
  for (int pick = 0; pick < MAXT; ++pick) {
    u32 lmin = 0xFFFFFFFFu;
    if (mk2) lmin = p0 + 2;
    if (mk1) lmin = p0 + 1;
    if (mk0) lmin = p0;
    u64 bal = __ballot(lmin != 0xFFFFFFFFu);
    if (bal != 0) {
      int src = (int)__ffsll((unsigned long long)bal) - 1;
      u32 wmin = __shfl(lmin, src, 64);
      if ((tid & 63) == 0) atomicMin(&slots[pick], wmin);
    }
    __syncthreads();
    u32 winpos = slots[pick];
    if (winpos == 0xFFFFFFFFu) { donepicks = pick; break; }
    u64 wk = key_s[winpos];
    float4 pb = box_s[winpos];
    if (tid == 0) {
      outS[pick] = __uint_as_float((u32)(wk >> 32));
      *(float4*)(outB + pick * 4) = pb;
      wbox[pick] = pb;
    }
    float pa = (pb.z - pb.x) * (pb.w - pb.y);
    if (mk0) {
      if (p0 == winpos) mk0 = 0;
      else {
        float yy1 = fmaxf(pb.x, mb0.x), xx1 = fmaxf(pb.y, mb0.y);
        float yy2 = fminf(pb.z, mb0.z), xx2 = fminf(pb.w, mb0.w);
        float inter = fmaxf(yy2 - yy1, 0.0f) * fmaxf(xx2 - xx1, 0.0f);
        float aj = (mb0.z - mb0.x) * (mb0.w - mb0.y);
        if (inter / (pa + aj - inter + 1e-8f) > 0.3f) mk0 = 0;
      }
    }
    if (mk1) {
      if (p0 + 1 == winpos) mk1 = 0;
      else {
        float yy1 = fmaxf(pb.x, mb1.x), xx1 = fmaxf(pb.y, mb1.y);
        float yy2 = fminf(pb.z, mb1.z), xx2 = fminf(pb.w, mb1.w);
        float inter = fmaxf(yy2 - yy1, 0.0f) * fmaxf(xx2 - xx1, 0.0f);
        float aj = (mb1.z - mb1.x) * (mb1.w - mb1.y);
        if (inter / (pa + aj - inter + 1e-8f) > 0.3f) mk1 = 0;
      }
    }
    if (mk2) {
      if (p0 + 2 == winpos) mk2 = 0;
      else {
        float yy1 = fmaxf(pb.x, mb2.x), xx1 = fmaxf(pb.y, mb2.y);
        float yy2 = fminf(pb.z, mb2.z), xx2 = fminf(pb.w, mb2.w);
        float inter = fmaxf(yy2 - yy1, 0.0f) * fmaxf(xx2 - xx1, 0.0f);
        float aj = (mb2.z - mb2.x) * (mb2.w - mb2.y);
        if (inter / (pa + aj - inter + 1e-8f) > 0.3f) mk2 = 0;
      }
    }
  }

  // ---- phase 2 (rare): chunk exhausted before 100 picks -> full pool fallback ----
  if (donepicks < MAXT) {
    __syncthreads();
    if (!sortedE) {
      if (!refined) {
        for (u32 i = tid; i < h; i += 1024) listE[i] = LEg[i];
      }
      bitonic_desc(listE, h, tid, 1024);
      sortedE = true;
    }
    __syncthreads();
    // pool = listA below chunk threshold (or all if chunkEmpty) + listE[takeE..R)
    for (u32 s = tid; s < g; s += 1024) {
      u64 kp = LAm[s];
      if (kp >= thrpack && (chunkEmpty || (u32)(kp >> 51) < B1k)) {
        u32 p = atomicAdd(&sh_Np, 1u);
        if (p < 5120u) pool_k[p] = kp;
      }
    }
    for (u32 j = takeE + tid; j < R; j += 1024) {
      u64 kp = listE[j];
      if (kp >= thrpack) {
        u32 p = atomicAdd(&sh_Np, 1u);
        if (p < 5120u) pool_k[p] = kp;
      }
    }
    __syncthreads();
    u32 Np = sh_Np; if (Np > 5120u) Np = 5120u;

    u64 key5[5]; float4 kb5[5];
    #pragma unroll
    for (int j = 0; j < 5; ++j) {
      u32 s = (u32)tid + (u32)j * 1024u;
      u64 kp = (s < Np) ? pool_k[s] : 0ULL;
      key5[j] = kp;
      if (kp) {
        u32 idx = 0xFFFFFFFFu - (u32)(kp & 0xFFFFFFFFull);
        kb5[j] = boxes4[bbase + idx];
      } else {
        kb5[j] = make_float4(0.f, 0.f, 0.f, 0.f);
      }
    }
    // pre-kill vs phase-1 winners
    for (int w = 0; w < donepicks; ++w) {
      float4 pb = wbox[w];
      float pa = (pb.z - pb.x) * (pb.w - pb.y);
      #pragma unroll
      for (int j = 0; j < 5; ++j) {
        if (key5[j]) {
          float4 bb = kb5[j];
          float yy1 = fmaxf(pb.x, bb.x), xx1 = fmaxf(pb.y, bb.y);
          float yy2 = fminf(pb.z, bb.z), xx2 = fminf(pb.w, bb.w);
          float inter = fmaxf(yy2 - yy1, 0.0f) * fmaxf(xx2 - xx1, 0.0f);
          float aj = (bb.z - bb.x) * (bb.w - bb.y);
          if (inter / (pa + aj - inter + 1e-8f) > 0.3f) key5[j] = 0ULL;
        }
      }
    }
    __syncthreads();
    for (int pick = donepicks; pick < MAXT; ++pick) {
      u64 m = key5[0];
      #pragma unroll
      for (int j = 1; j < 5; ++j) if (key5[j] > m) m = key5[j];
      #pragma unroll
      for (int off = 1; off < 64; off <<= 1) {
        u64 o = __shfl_xor(m, off);
        if (o > m) m = o;
      }
      if ((tid & 63) == 0 && m != 0ULL) atomicMax((unsigned long long*)&slots64[pick], m);
      __syncthreads();
      u64 win = slots64[pick];
      if (win == 0ULL) {
        for (int p = pick + tid; p < MAXT; p += 1024) {
          outS[p] = -1.0f;
          *(float4*)(outB + p * 4) = make_float4(0.f, 0.f, 0.f, 0.f);
        }
        break;
      }
      u32 widx = 0xFFFFFFFFu - (u32)(win & 0xFFFFFFFFull);
      float4 pb = boxes4[bbase + widx];
      #pragma unroll
      for (int j = 0; j < 5; ++j) if (key5[j] == win) key5[j] = 0ULL;
      if (tid == 0) {
        outS[pick] = __uint_as_float((u32)(win >> 32));
        *(float4*)(outB + pick * 4) = pb;
      }
      float pa = (pb.z - pb.x) * (pb.w - pb.y);
      #pragma unroll
      for (int j = 0; j < 5; ++j) {
        if (key5[j] != 0ULL) {
          float4 bb = kb5[j];
          float yy1 = fmaxf(pb.x, bb.x), xx1 = fmaxf(pb.y, bb.y);
          float yy2 = fminf(pb.z, bb.z), xx2 = fminf(pb.w, bb.w);
          float inter = fmaxf(yy2 - yy1, 0.0f) * fmaxf(xx2 - xx1, 0.0f);
          float aj = (bb.z - bb.x) * (bb.w - bb.y);
          if (inter / (pa + aj - inter + 1e-8f) > 0.3f) key5[j] = 0ULL;
        }
      }
    }
  }
}

// ---------------- final per-batch top-100: 90-way merge, 1 barrier/iter ----------------
__global__ __launch_bounds__(128) void merge_kernel(
    const float* __restrict__ nms_s, const float* __restrict__ nms_b,
    float* __restrict__ out_b, float* __restrict__ out_s,
    float* __restrict__ out_c, float* __restrict__ out_v)
{
  int b = blockIdx.x, tid = threadIdx.x;   // 128 threads = 2 waves
  __shared__ float ssc[NCLS * MAXT];
  __shared__ u64 slots[MAXT];
  for (int i = tid; i < NCLS * MAXT; i += 128) ssc[i] = nms_s[(size_t)b * NCLS * MAXT + i];
  for (int i = tid; i < MAXT; i += 128) slots[i] = 0ULL;
  int c = tid, hh = 0;
  auto mkkey = [&](int cc, int hx) -> u64 {
    if (cc >= NCLS || hx >= MAXT) return 0ULL;
    float s = ssc[cc * MAXT + hx];
    u32 u = __float_as_uint(s);
    u = (u & 0x80000000u) ? ~u : (u | 0x80000000u);
    u32 flat = (u32)(cc * MAXT + hx);
    return ((u64)u << 32) | (u64)(0xFFFFFFFFu - flat);
  };
  __syncthreads();
  u64 k = mkkey(c, hh);
  int vcnt = 0;
  for (int t = 0; t < MAXT; ++t) {
    u64 m = k;
    #pragma unroll
    for (int off = 1; off < 64; off <<= 1) {
      u64 o = __shfl_xor(m, off);
      if (o > m) m = o;
    }
    if ((tid & 63) == 0 && m != 0ULL) atomicMax((unsigned long long*)&slots[t], m);
    __syncthreads();
    u64 win = slots[t];
    u32 u = (u32)(win >> 32);
    u32 bits = (u & 0x80000000u) ? (u ^ 0x80000000u) : ~u;
    float s = __uint_as_float(bits);
    u32 flat = 0xFFFFFFFFu - (u32)(win & 0xFFFFFFFFull);
    int cls = (int)(flat / MAXT), pos = (int)(flat % MAXT);
    if (tid == 0) {
      out_s[b * MAXT + t] = s;
      out_c[b * MAXT + t] = (float)(cls + 1);
      *(float4*)(out_b + ((size_t)b * MAXT + t) * 4) =
          *(const float4*)(nms_b + (((size_t)b * NCLS + cls) * MAXT + pos) * 4);
      if (s > -1.0f) vcnt++;
    }
    if (c == cls) { hh++; k = mkkey(c, hh); }
  }
  if (tid == 0) out_v[b] = (float)vcnt;
}

extern "C" void kernel_launch(void* const* d_in, const int* in_sizes, int n_in,
                              void* d_out, int out_size, void* d_ws, size_t ws_size,
                              hipStream_t stream)
{
  const float* box[5]; const float* cls[5]; const float* anc[5];
  bool interleaved = (in_sizes[1] == 2 * 57600 * 91);   // setup_inputs dict order
  if (interleaved) {
    for (int l = 0; l < 5; ++l) {
      box[l] = (const float*)d_in[3 * l + 0];
      cls[l] = (const float*)d_in[3 * l + 1];
      anc[l] = (const float*)d_in[3 * l + 2];
    }
  } else {
    for (int l = 0; l < 5; ++l) {
      box[l] = (const float*)d_in[l];
      cls[l] = (const float*)d_in[5 + l];
      anc[l] = (const float*)d_in[10 + l];
    }
  }
  const float* img = (const float*)d_in[15];

  float* ws = (float*)d_ws;
  float* boxes_ws = ws;                          // 613800 f
  float* scores_t = boxes_ws + 613800;           // 180*76736       = 13812480 f
  u32*   hist_g   = (u32*)(scores_t + 13812480); // 180*4096        = 737280 u32
  u32*   cntA_g   = hist_g + 737280;             // 180
  u32*   cntE_g   = cntA_g + 180;                // 180
  u32*   B_g      = cntE_g + 180;                // 180
  u64*   listA_g  = (u64*)(B_g + 180);           // 180*5120 u64
  u64*   listE_g  = listA_g + 180 * 5120;        // 180*2048 u64
  float* nms_s    = (float*)(listE_g + 180 * 2048);  // 18000 f
  float* nms_b    = nms_s + 18000;               // 72000 f

  decode_kernel<<<600, 256, 0, stream>>>(
      box[0], box[1], box[2], box[3], box[4],
      anc[0], anc[1], anc[2], anc[3], anc[4], img, boxes_ws, hist_g, scores_t);

  transpose_kernel<<<2402, 256, 0, stream>>>(cls[0], cls[1], cls[2], cls[3], cls[4], scores_t);

  hist_kernel<<<720, 512, 0, stream>>>(scores_t, hist_g);

  collect_kernel<<<720, 512, 0, stream>>>(scores_t, hist_g, listA_g, listE_g,
                                          cntA_g, cntE_g, B_g);

  nms_kernel<<<180, 1024, 0, stream>>>(scores_t, boxes_ws, listA_g, listE_g,
                                       cntA_g, cntE_g, B_g, hist_g, nms_s, nms_b);

  float* out_b = (float*)d_out;  // [2][100][4]
  float* out_s = out_b + 800;    // [2][100]
  float* out_c = out_s + 200;    // [2][100]
  float* out_v = out_c + 200;    // [2]
  merge_kernel<<<2, 128, 0, stream>>>(nms_s, nms_b, out_b, out_s, out_c, out_v);
}

// Round 5
// 214.814 us; speedup vs baseline: 6.1072x; 1.1247x over previous
//
#include <hip/hip_runtime.h>
#include <hip/hip_bf16.h>

typedef unsigned long long u64;
typedef unsigned int u32;

#define A_TOTAL 76725
#define A_PAD   76736            /* padded to /4 for float4 loads */
#define QCH     (A_PAD / 4)
#define NCLS 90
#define KTOP 5000u
#define MAXT 100
#define KTHR 0x3D4CCCCDu         /* bits of 0.05f */
#define NTH  256                 /* nms threads */

__device__ __forceinline__ u64 pack_key(u32 k, u32 i) {
  return ((u64)k << 32) | (u64)(0xFFFFFFFFu - i);
}

// Legacy cutoff scan used by collect (wave 0). Smallest bucket B with sum(b>=B) >= need.
__device__ __forceinline__ u32 scan_cut(const u32* gh, u32 need, int tid) {
  int base = 4095 - tid * 64;
  u32 s = 0;
  #pragma unroll
  for (int j = 0; j < 64; ++j) s += gh[base - j];
  u32 incl = s;
  #pragma unroll
  for (int off = 1; off < 64; off <<= 1) {
    u32 o = __shfl_up(incl, off, 64);
    if (tid >= off) incl += o;
  }
  u32 excl = incl - s;
  bool cross = (excl < need) && (incl >= need);
  u64 bal = __ballot(cross);
  int cl = __ffsll((unsigned long long)bal) - 1;
  int cbase = 4095 - cl * 64;
  u32 cexcl = __shfl(excl, cl, 64);
  u32 v = gh[cbase - tid];
  u32 incl2 = v;
  #pragma unroll
  for (int off = 1; off < 64; off <<= 1) {
    u32 o = __shfl_up(incl2, off, 64);
    if (tid >= off) incl2 += o;
  }
  bool c2 = (cexcl + incl2 >= need) && (cexcl + incl2 - v < need);
  u64 bal2 = __ballot(c2);
  int j2 = __ffsll((unsigned long long)bal2) - 1;
  return (u32)(cbase - j2);
}

// Full wave-0 cut with totals: B = smallest bucket with count(>=B) >= need.
// incl = count(>=B), above = count(>B), total = count(all). Valid only if total >= need,
// otherwise returns total and caller must branch.
__device__ __forceinline__ void cut4096w(const u32* hh, u32 need, int wl,
                                         u32& B, u32& incl, u32& above, u32& total) {
  int lo = wl << 6;
  u32 s = 0;
  #pragma unroll
  for (int j = 0; j < 64; ++j) s += hh[lo + j];
  u32 suf = s;
  #pragma unroll
  for (int off = 1; off < 64; off <<= 1) {
    u32 v = __shfl_down(suf, off, 64);
    if (wl < 64 - off) suf += v;
  }
  total = __shfl(suf, 0, 64);
  if (total < need) { B = 0; incl = total; above = 0; return; }
  u32 sufnext = suf - s;
  bool cross = (suf >= need) && (sufnext < need);
  u64 bal = __ballot(cross);
  int gl = (int)__ffsll((unsigned long long)bal) - 1;
  int glo = gl << 6;
  u32 aboveG = __shfl(sufnext, gl, 64);
  u32 hb = hh[glo + wl];
  u32 sufb = hb;
  #pragma unroll
  for (int off = 1; off < 64; off <<= 1) {
    u32 v = __shfl_down(sufb, off, 64);
    if (wl < 64 - off) sufb += v;
  }
  bool c2 = (aboveG + sufb >= need) && (aboveG + sufb - hb < need);
  u64 bal2 = __ballot(c2);
  int jB = (int)__ffsll((unsigned long long)bal2) - 1;
  B = (u32)(glo + jB);
  incl = aboveG + __shfl(sufb, jB, 64);
  above = incl - __shfl(hb, jB, 64);
}

// Block-cooperative descending bitonic sort of a[0..n) padded to pow2 with 0.
__device__ __forceinline__ void bitonic_desc(u64* a, u32 n, int tid, int nth) {
  u32 P = 2; while (P < n) P <<= 1;
  for (u32 i = tid; i < P; i += nth) if (i >= n) a[i] = 0ULL;
  __syncthreads();
  for (u32 kk = 2; kk <= P; kk <<= 1) {
    for (u32 jj = kk >> 1; jj; jj >>= 1) {
      for (u32 i = tid; i < P; i += nth) {
        u32 ixj = i ^ jj;
        if (ixj > i) {
          u64 x = a[i], y = a[ixj];
          bool up = ((i & kk) == 0);
          if (up ? (x < y) : (x > y)) { a[i] = y; a[ixj] = x; }
        }
      }
      __syncthreads();
    }
  }
}

// ---------------- decode + clip (+ zero hist/counters/pad) ----------------
__global__ __launch_bounds__(256) void decode_kernel(
    const float* __restrict__ bx0, const float* __restrict__ bx1, const float* __restrict__ bx2,
    const float* __restrict__ bx3, const float* __restrict__ bx4,
    const float* __restrict__ an0, const float* __restrict__ an1, const float* __restrict__ an2,
    const float* __restrict__ an3, const float* __restrict__ an4,
    const float* __restrict__ img, float* __restrict__ boxes,
    u32* __restrict__ zero_base, float* __restrict__ scores_t)
{
  int t = blockIdx.x * blockDim.x + threadIdx.x;
  int nth = gridDim.x * blockDim.x;
  for (int i = t; i < 180 * 4096 + 540; i += nth) zero_base[i] = 0;
  if (t < 180 * (A_PAD - A_TOTAL)) {
    int lane = t / (A_PAD - A_TOTAL), off = t % (A_PAD - A_TOTAL);
    scores_t[(size_t)lane * A_PAD + A_TOTAL + off] = 0.0f;
  }
  if (t >= 2 * A_TOTAL) return;
  int b = t / A_TOTAL, a = t % A_TOTAL;
  const float* bp; const float* ap; int al; int nl;
  if (a < 57600)      { bp = bx0; ap = an0; al = a;          nl = 57600; }
  else if (a < 72000) { bp = bx1; ap = an1; al = a - 57600;  nl = 14400; }
  else if (a < 75600) { bp = bx2; ap = an2; al = a - 72000;  nl = 3600;  }
  else if (a < 76500) { bp = bx3; ap = an3; al = a - 75600;  nl = 900;   }
  else                { bp = bx4; ap = an4; al = a - 76500;  nl = 225;   }
  float4 e  = *(const float4*)(bp + ((size_t)b * nl + al) * 4);
  float4 an = *(const float4*)(ap + ((size_t)b * nl + al) * 4);
  const float CLIP = 4.135166556742356f; // log(1000/16)
  float ah  = an.z - an.x + 1.0f;
  float aw  = an.w - an.y + 1.0f;
  float ayc = an.x + 0.5f * ah;
  float axc = an.y + 0.5f * aw;
  float dh = fminf(e.z, CLIP), dw = fminf(e.w, CLIP);
  float yc = e.x * ah + ayc;
  float xc = e.y * aw + axc;
  float h  = expf(dh) * ah;
  float w  = expf(dw) * aw;
  float ymin = yc - 0.5f * h;
  float xmin = xc - 0.5f * w;
  float ymax = ymin + h - 1.0f;
  float xmax = xmin + w - 1.0f;
  float H = img[b * 2 + 0], W = img[b * 2 + 1];
  float4 o;
  o.x = fminf(fmaxf(ymin, 0.0f), H);
  o.y = fminf(fmaxf(xmin, 0.0f), W);
  o.z = fminf(fmaxf(ymax, 0.0f), H);
  o.w = fminf(fmaxf(xmax, 0.0f), W);
  *(float4*)(boxes + (size_t)t * 4) = o;
}

// ---------------- sigmoid + transpose to [B,90,A_PAD] ----------------
__global__ __launch_bounds__(256) void transpose_kernel(
    const float* __restrict__ c3, const float* __restrict__ c4, const float* __restrict__ c5,
    const float* __restrict__ c6, const float* __restrict__ c7, float* __restrict__ scores_t)
{
  __shared__ float lds[64 * 91];
  int blk = blockIdx.x;
  int lvl, local;
  if      (blk < 1800) { lvl = 0; local = blk; }
  else if (blk < 2250) { lvl = 1; local = blk - 1800; }
  else if (blk < 2364) { lvl = 2; local = blk - 2250; }
  else if (blk < 2394) { lvl = 3; local = blk - 2364; }
  else                 { lvl = 4; local = blk - 2394; }
  const int ns[5]    = {57600, 14400, 3600, 900, 225};
  const int bases[5] = {0, 57600, 72000, 75600, 76500};
  const int tl[5]    = {900, 225, 57, 15, 4};
  const float* cls = (lvl == 0) ? c3 : (lvl == 1) ? c4 : (lvl == 2) ? c5 : (lvl == 3) ? c6 : c7;
  int n = ns[lvl], base = bases[lvl], tiles = tl[lvl];
  int b = local / tiles, tile = local % tiles;
  int a0 = tile * 64;
  int cnt = n - a0; if (cnt > 64) cnt = 64;
  const float* src = cls + ((size_t)b * n + a0) * 91;
  int total = cnt * 91;
  for (int i = threadIdx.x; i < total; i += 256) lds[i] = src[i];
  __syncthreads();
  for (int j = threadIdx.x; j < NCLS * 64; j += 256) {
    int c = j >> 6, a = j & 63;
    if (a < cnt) {
      float x = lds[a * 91 + c + 1];
      scores_t[((size_t)(b * NCLS + c)) * A_PAD + base + a0 + a] = 1.0f / (1.0f + expf(-x));
    }
  }
}

// ---------------- per-lane global histograms (2x replicated vs atomic contention) ----------------
__global__ __launch_bounds__(512) void hist_kernel(const float* __restrict__ scores_t,
                                                   u32* __restrict__ hist_g)
{
  __shared__ u32 hist[8192];
  int tid = threadIdx.x;
  int lane = blockIdx.x >> 2, q = blockIdx.x & 3;
  for (int i = tid; i < 8192; i += 512) hist[i] = 0;
  __syncthreads();
  u32 par = (u32)(tid & 1);
  const float4* S4 = (const float4*)(scores_t + (size_t)lane * A_PAD + q * QCH);
  for (int i = tid; i < QCH / 4; i += 512) {
    float4 v = S4[i];
    atomicAdd(&hist[((__float_as_uint(v.x) >> 19) << 1) | par], 1u);
    atomicAdd(&hist[((__float_as_uint(v.y) >> 19) << 1) | par], 1u);
    atomicAdd(&hist[((__float_as_uint(v.z) >> 19) << 1) | par], 1u);
    atomicAdd(&hist[((__float_as_uint(v.w) >> 19) << 1) | par], 1u);
  }
  __syncthreads();
  u32* gh = hist_g + (size_t)lane * 4096;
  for (int i = tid; i < 4096; i += 512) {
    u32 v = hist[2 * i] + hist[2 * i + 1];
    if (v) atomicAdd(&gh[i], v);
  }
}

// ---------------- collect candidates into per-lane global lists ----------------
__global__ __launch_bounds__(512) void collect_kernel(
    const float* __restrict__ scores_t, const u32* __restrict__ hist_g,
    u64* __restrict__ listA_g, u64* __restrict__ listE_g,
    u32* __restrict__ cntA_g, u32* __restrict__ cntE_g, u32* __restrict__ B_g)
{
  __shared__ u64 bufA[5120];
  __shared__ u64 bufE[2048];
  __shared__ u32 sh_B, sh_cA, sh_cE, sh_baseA, sh_baseE;
  int tid = threadIdx.x;
  int lane = blockIdx.x >> 2, q = blockIdx.x & 3;
  const u32* gh = hist_g + (size_t)lane * 4096;
  if (tid < 64) {
    u32 B = scan_cut(gh, KTOP, tid);
    if (tid == 0) { sh_B = B; sh_cA = 0; sh_cE = 0; }
  }
  __syncthreads();
  u32 B = sh_B;
  if (tid == 0 && q == 0) B_g[lane] = B;
  const float4* S4 = (const float4*)(scores_t + (size_t)lane * A_PAD + q * QCH);
  int base_idx = q * QCH;
  for (int i = tid; i < QCH / 4; i += 512) {
    float4 v = S4[i];
    u32 ks[4] = {__float_as_uint(v.x), __float_as_uint(v.y), __float_as_uint(v.z), __float_as_uint(v.w)};
    #pragma unroll
    for (int j = 0; j < 4; ++j) {
      u32 k = ks[j], bkt = k >> 19;
      u32 idx = (u32)(base_idx + i * 4 + j);
      if (bkt > B) {
        u32 p = atomicAdd(&sh_cA, 1u);
        if (p < 5120u) bufA[p] = pack_key(k, idx);
      } else if (bkt == B) {
        u32 p = atomicAdd(&sh_cE, 1u);
        if (p < 2048u) bufE[p] = pack_key(k, idx);
      }
    }
  }
  __syncthreads();
  u32 cA = sh_cA; if (cA > 5120u) cA = 5120u;
  u32 cE = sh_cE; if (cE > 2048u) cE = 2048u;
  if (tid == 0) {
    sh_baseA = atomicAdd(&cntA_g[lane], sh_cA);
    sh_baseE = atomicAdd(&cntE_g[lane], sh_cE);
  }
  __syncthreads();
  u32 bA = sh_baseA, bE = sh_baseE;
  u64* LA = listA_g + (size_t)lane * 5120;
  u64* LE = listE_g + (size_t)lane * 2048;
  for (u32 i = tid; i < cA; i += 512) { u32 d = bA + i; if (d < 5120u) LA[d] = bufA[i]; }
  for (u32 i = tid; i < cE; i += 512) { u32 d = bE + i; if (d < 2048u) LE[d] = bufE[i]; }
}

// ---------------- per-lane NMS: affine counting-sort chunk + wave-0 lazy greedy scan ----------------
__global__ __launch_bounds__(NTH) void nms_kernel(
    const float* __restrict__ scores_t, const float* __restrict__ boxes,
    u64* __restrict__ listA_g, u64* __restrict__ listE_g,
    const u32* __restrict__ cntA_g, const u32* __restrict__ cntE_g, const u32* __restrict__ B_g,
    float* __restrict__ nms_s, float* __restrict__ nms_b)
{
  __shared__ u64 key_s[2048];                   // 16 KB sorted chunk keys
  __shared__ __align__(16) float4 box_s[2048];  // 32 KB chunk boxes; scratch u32[8192] during build
  __shared__ u64 ebuf[2048];                    // 16 KB: histL u32[4096] / listE
  __shared__ float4 wbox[MAXT];
  __shared__ u32 wtot[4];
  __shared__ u64 sh_minPrev;
  __shared__ u32 sh_w, sh_done, sh_eidx, sh_Rthr, sh_eSorted, sh_big;
  __shared__ u32 sh_B, sh_incl, sh_above, sh_total;
  __shared__ u32 sh_c0, sh_c1, sh_B2;

  u32* histL  = (u32*)ebuf;
  u32* cntArr = (u32*)box_s;

  int tid = threadIdx.x;
  int lane = blockIdx.x;
  int b = lane / NCLS;
  const float4* boxes4 = (const float4*)boxes;
  size_t bbase = (size_t)b * A_TOTAL;
  const u64 thrpack = ((u64)KTHR) << 32;

  u32 g = cntA_g[lane];
  u32 h = cntE_g[lane];
  u32 B = B_g[lane];
  u64* LAm = listA_g + (size_t)lane * 5120;
  u64* LEg = listE_g + (size_t)lane * 2048;

  if (tid == 0) {
    sh_w = 0; sh_done = 0; sh_eidx = 0; sh_eSorted = 0; sh_minPrev = ~0ull;
  }

  // ---- rare: global listE overflowed -> refine boundary on bits [18:7], spill listE ----
  if (h > 2048u) {
    const float* S = scores_t + (size_t)lane * A_PAD;
    for (int i = tid; i < 4096; i += NTH) histL[i] = 0;
    if (tid == 0) { sh_c0 = 0; sh_c1 = 0; }
    __syncthreads();
    for (int i = tid; i < A_PAD; i += NTH) {
      u32 k = __float_as_uint(S[i]);
      if ((k >> 19) == B) atomicAdd(&histL[(k >> 7) & 0xFFFu], 1u);
    }
    __syncthreads();
    u32 R1 = KTOP - g;
    if (tid < 64) {
      u32 Bx, ix, ax, tx;
      cut4096w(histL, R1, tid, Bx, ix, ax, tx);
      if (tid == 0) sh_B2 = Bx;
    }
    __syncthreads();
    u32 B2 = sh_B2;
    __syncthreads();   // histL reads done before ebuf reused as listE
    for (int i = tid; i < A_PAD; i += NTH) {
      u32 k = __float_as_uint(S[i]);
      if ((k >> 19) == B) {
        u32 sb = (k >> 7) & 0xFFFu;
        if (sb > B2) {
          u32 p = atomicAdd(&sh_c0, 1u);
          if (g + p < 5120u) LAm[g + p] = pack_key(k, (u32)i);
        } else if (sb == B2) {
          u32 p = atomicAdd(&sh_c1, 1u);
          if (p < 2048u) ebuf[p] = pack_key(k, (u32)i);
        }
      }
    }
    __syncthreads();
    g += sh_c0; if (g > 5120u) g = 5120u;
    h = sh_c1;  if (h > 2048u) h = 2048u;
    for (u32 i = tid; i < h; i += NTH) LEg[i] = ebuf[i];   // spill (syncthreads drains vmem)
    __syncthreads();
  }
  g = (g > 5120u) ? 5120u : g;
  u32 R = (g < KTOP) ? (KTOP - g) : 0u;
  if (R > h) R = h;

  // ---- listA keys -> registers (threshold-filtered; 0 = empty) ----
  u64 ak[20];
  #pragma unroll
  for (int r = 0; r < 20; ++r) {
    u32 s = (u32)tid + (u32)r * NTH;
    u64 kp = (s < g) ? LAm[s] : 0ull;
    if (kp < thrpack) kp = 0ull;
    ak[r] = kp;
  }

  float* outS = nms_s + (size_t)lane * MAXT;
  float* outB = nms_b + (size_t)lane * MAXT * 4;

  const float LO0  = 0.04f;
  const float INV0 = 4096.0f / (1.001f - 0.04f);

  // ================= segment loop =================
  for (int seg = 0; seg < 7200; ++seg) {
    __syncthreads();
    if (sh_w >= MAXT || sh_done) break;
    u64 minPrev = sh_minPrev;

    // ---- cut descent ----
    int digLvl = 0;
    u32 A_B0 = 0, A_B1 = 0;
    float lo1 = 0.f, inv1 = 0.f;
    u64 kMask = 0, kPref = 0;
    int m1shift = 32;
    int selMode = -1;          // 0=all, 1=keep boundary (d>=B), 2=above only (d>B)
    u32 selB = 0;
    u32 C = 0;
    bool fromE = false;

    for (int lvl = 0; lvl < 8; ++lvl) {
      for (int i = tid; i < 4096; i += NTH) histL[i] = 0;
      __syncthreads();
      #pragma unroll
      for (int r = 0; r < 20; ++r) {
        u64 k = ak[r];
        if (!k || k >= minPrev) continue;
        float s = __uint_as_float((u32)(k >> 32));
        if (digLvl >= 1) { int d0 = (int)((s - LO0) * INV0); d0 = min(max(d0, 0), 4095); if ((u32)d0 != A_B0) continue; }
        if (digLvl >= 2) { int d1 = (int)((s - lo1) * inv1); d1 = min(max(d1, 0), 4095); if ((u32)d1 != A_B1) continue; }
        if (digLvl >= 3 && ((k & kMask) != kPref)) continue;
        u32 d;
        if (digLvl == 0)      { int t0 = (int)((s - LO0) * INV0); d = (u32)min(max(t0, 0), 4095); }
        else if (digLvl == 1) { int t1 = (int)((s - lo1) * inv1); d = (u32)min(max(t1, 0), 4095); }
        else                  d = (u32)((k >> m1shift) & 0xFFFull);
        atomicAdd(&histL[d], 1u);
      }
      __syncthreads();
      if (tid < 64) {
        u32 Bx, ix, ax, tx;
        cut4096w(histL, 1024u, tid, Bx, ix, ax, tx);
        if (tid == 0) { sh_B = Bx; sh_incl = ix; sh_above = ax; sh_total = tx; }
      }
      __syncthreads();
      u32 total = sh_total, incl = sh_incl, above = sh_above, Bx = sh_B;
      if (total == 0u)   { fromE = true; break; }
      if (total < 1024u) { selMode = 0; C = total; break; }
      if (incl <= 2048u) { selMode = 1; selB = Bx; C = incl; break; }
      if (above > 0u)    { selMode = 2; selB = Bx; C = above; break; }
      // descend into fat bucket Bx
      if (digLvl == 0) {
        A_B0 = Bx;
        lo1 = LO0 + (float)Bx / INV0;
        inv1 = INV0 * 4096.0f;
        digLvl = 1;
      } else if (digLvl == 1) {
        A_B1 = Bx;
        digLvl = 2; m1shift = 32;
      } else {
        kPref |= ((u64)Bx << m1shift);
        kMask |= (0xFFFull << m1shift);
        m1shift -= 12;
        digLvl++;
      }
      __syncthreads();
    }

    if (fromE) {
      // ---- listA exhausted: consume sorted listE top-R ----
      if (!sh_eSorted) {
        for (u32 i = tid; i < h; i += NTH) ebuf[i] = LEg[i];
        __syncthreads();
        bitonic_desc(ebuf, h, tid, NTH);
        for (u32 i = tid; i < h; i += NTH) LEg[i] = ebuf[i];   // spill sorted
        if (tid == 0) {
          u32 lo = 0, hi2 = h;
          while (lo < hi2) { u32 mid = (lo + hi2) >> 1; if (ebuf[mid] >= thrpack) lo = mid + 1; else hi2 = mid; }
          sh_Rthr = (R < lo) ? R : lo;
          sh_eSorted = 1;
        }
        __syncthreads();
      }
      u32 eidx = sh_eidx;
      u32 take = (sh_Rthr > eidx) ? (sh_Rthr - eidx) : 0u;
      if (take > 2048u) take = 2048u;
      if (take == 0u) { if (tid == 0) sh_done = 1; continue; }
      for (u32 i = tid; i < take; i += NTH) key_s[i] = LEg[eidx + i];
      C = take;
      if (tid == 0) sh_eidx = eidx + take;
    } else {
      // ---- prefix bases in-place over histL (descending exclusive) ----
      u32 hloc[16];
      {
        int t0 = tid << 4;
        u32 ssum = 0;
        #pragma unroll
        for (int j = 0; j < 16; ++j) { hloc[j] = histL[t0 + j]; ssum += hloc[j]; }
        int wl = tid & 63, wid = tid >> 6;
        u32 suf = ssum;
        #pragma unroll
        for (int off = 1; off < 64; off <<= 1) {
          u32 v = __shfl_down(suf, off, 64);
          if (wl < 64 - off) suf += v;
        }
        if (wl == 0) wtot[wid] = suf;
        __syncthreads();
        u32 cross = 0;
        for (int w2 = wid + 1; w2 < 4; ++w2) cross += wtot[w2];
        u32 run = (suf - ssum) + cross;
        #pragma unroll
        for (int j = 15; j >= 0; --j) { u32 base2 = run; run += hloc[j]; histL[t0 + j] = base2; }
      }
      for (int i = tid; i < 4096; i += NTH) cntArr[i] = 0;
      if (tid == 0) sh_big = 0;
      __syncthreads();
      // ---- scatter ----
      #pragma unroll
      for (int r = 0; r < 20; ++r) {
        u64 k = ak[r];
        if (!k || k >= minPrev) continue;
        float s = __uint_as_float((u32)(k >> 32));
        if (digLvl >= 1) { int d0 = (int)((s - LO0) * INV0); d0 = min(max(d0, 0), 4095); if ((u32)d0 != A_B0) continue; }
        if (digLvl >= 2) { int d1 = (int)((s - lo1) * inv1); d1 = min(max(d1, 0), 4095); if ((u32)d1 != A_B1) continue; }
        if (digLvl >= 3 && ((k & kMask) != kPref)) continue;
        u32 d;
        if (digLvl == 0)      { int t0x = (int)((s - LO0) * INV0); d = (u32)min(max(t0x, 0), 4095); }
        else if (digLvl == 1) { int t1x = (int)((s - lo1) * inv1); d = (u32)min(max(t1x, 0), 4095); }
        else                  d = (u32)((k >> m1shift) & 0xFFFull);
        if (selMode == 1)      { if (d < selB) continue; }
        else if (selMode == 2) { if (d <= selB) continue; }
        u32 pos = histL[d] + atomicAdd(&cntArr[d], 1u);
        if (pos < 2048u) key_s[pos] = k;
      }
      __syncthreads();
      // ---- per-bucket minisort (full-key desc) ----
      {
        int t0 = tid << 4;
        for (int j = 0; j < 16; ++j) {
          u32 bkt = (u32)(t0 + j);
          u32 c = cntArr[bkt];
          if (c >= 2u) {
            if (c <= 48u) {
              u32 basep = histL[bkt];
              for (u32 a2 = 1; a2 < c; ++a2) {
                u64 kv = key_s[basep + a2];
                int bi = (int)a2 - 1;
                while (bi >= 0 && key_s[basep + bi] < kv) { key_s[basep + bi + 1] = key_s[basep + bi]; --bi; }
                key_s[basep + bi + 1] = kv;
              }
            } else sh_big = 1;
          }
        }
      }
      __syncthreads();
      if (sh_big) bitonic_desc(key_s, C, tid, NTH);
      if (tid == 0) sh_minPrev = key_s[C - 1];
    }
    __syncthreads();

    // ---- gather chunk boxes (overwrites scratch) ----
    for (u32 p = tid; p < C; p += NTH) {
      u32 idx = 0xFFFFFFFFu - (u32)(key_s[p] & 0xFFFFFFFFull);
      box_s[p] = boxes4[bbase + idx];
    }
    __syncthreads();

    // ---- lazy greedy scan (wave 0 only, no barriers) ----
    if (tid < 64) {
      int wl = tid;
      int w = (int)sh_w;
      u32 cur = 0;
      while (w < MAXT && cur < C) {
        u32 p = cur + (u32)wl;
        bool aliveL = (p < C);
        u64 kk = aliveL ? key_s[p] : 0ull;
        float4 mybox;
        if (aliveL) mybox = box_s[p];
        float myarea = aliveL ? (mybox.z - mybox.x) * (mybox.w - mybox.y) : 0.f;
        for (int j = 0; j < w; ++j) {
          if (aliveL) {
            float4 pb = wbox[j];
            float yy1 = fmaxf(pb.x, mybox.x), xx1 = fmaxf(pb.y, mybox.y);
            float yy2 = fminf(pb.z, mybox.z), xx2 = fminf(pb.w, mybox.w);
            float inter = fmaxf(yy2 - yy1, 0.0f) * fmaxf(xx2 - xx1, 0.0f);
            float pa = (pb.z - pb.x) * (pb.w - pb.y);
            if (inter / (pa + myarea - inter + 1e-8f) > 0.3f) aliveL = false;
          }
        }
        for (;;) {
          u64 bal = __ballot(aliveL);
          if (bal == 0ull) break;
          int js = (int)__ffsll((unsigned long long)bal) - 1;
          float4 pb;
          pb.x = __shfl(mybox.x, js, 64);
          pb.y = __shfl(mybox.y, js, 64);
          pb.z = __shfl(mybox.z, js, 64);
          pb.w = __shfl(mybox.w, js, 64);
          u64 wk = __shfl(kk, js, 64);
          if (wl == 0) {
            outS[w] = __uint_as_float((u32)(wk >> 32));
            *(float4*)(outB + w * 4) = pb;
            wbox[w] = pb;
          }
          w++;
          if (w >= MAXT) break;
          if (wl <= js) aliveL = false;
          else if (aliveL) {
            float yy1 = fmaxf(pb.x, mybox.x), xx1 = fmaxf(pb.y, mybox.y);
            float yy2 = fminf(pb.z, mybox.z), xx2 = fminf(pb.w, mybox.w);
            float inter = fmaxf(yy2 - yy1, 0.0f) * fmaxf(xx2 - xx1, 0.0f);
            float pa = (pb.z - pb.x) * (pb.w - pb.y);
            if (inter / (pa + myarea - inter + 1e-8f) > 0.3f) aliveL = false;
          }
        }
        cur += 64;
      }
      if (wl == 0) sh_w = (u32)w;
    }
  }

  // ---- padding like reference ----
  __syncthreads();
  u32 w = sh_w;
  for (u32 p = w + (u32)tid; p < MAXT; p += NTH) {
    outS[p] = -1.0f;
    *(float4*)(outB + p * 4) = make_float4(0.f, 0.f, 0.f, 0.f);
  }
}

// ---------------- final per-batch top-100: 90-way merge, 1 barrier/iter ----------------
__global__ __launch_bounds__(128) void merge_kernel(
    const float* __restrict__ nms_s, const float* __restrict__ nms_b,
    float* __restrict__ out_b, float* __restrict__ out_s,
    float* __restrict__ out_c, float* __restrict__ out_v)
{
  int b = blockIdx.x, tid = threadIdx.x;
  __shared__ float ssc[NCLS * MAXT];
  __shared__ u64 slots[MAXT];
  for (int i = tid; i < NCLS * MAXT; i += 128) ssc[i] = nms_s[(size_t)b * NCLS * MAXT + i];
  for (int i = tid; i < MAXT; i += 128) slots[i] = 0ULL;
  int c = tid, hh = 0;
  auto mkkey = [&](int cc, int hx) -> u64 {
    if (cc >= NCLS || hx >= MAXT) return 0ULL;
    float s = ssc[cc * MAXT + hx];
    u32 u = __float_as_uint(s);
    u = (u & 0x80000000u) ? ~u : (u | 0x80000000u);
    u32 flat = (u32)(cc * MAXT + hx);
    return ((u64)u << 32) | (u64)(0xFFFFFFFFu - flat);
  };
  __syncthreads();
  u64 k = mkkey(c, hh);
  int vcnt = 0;
  for (int t = 0; t < MAXT; ++t) {
    u64 m = k;
    #pragma unroll
    for (int off = 1; off < 64; off <<= 1) {
      u64 o = __shfl_xor(m, off);
      if (o > m) m = o;
    }
    if ((tid & 63) == 0 && m != 0ULL) atomicMax((unsigned long long*)&slots[t], m);
    __syncthreads();
    u64 win = slots[t];
    u32 u = (u32)(win >> 32);
    u32 bits = (u & 0x80000000u) ? (u ^ 0x80000000u) : ~u;
    float s = __uint_as_float(bits);
    u32 flat = 0xFFFFFFFFu - (u32)(win & 0xFFFFFFFFull);
    int cls = (int)(flat / MAXT), pos = (int)(flat % MAXT);
    if (tid == 0) {
      out_s[b * MAXT + t] = s;
      out_c[b * MAXT + t] = (float)(cls + 1);
      *(float4*)(out_b + ((size_t)b * MAXT + t) * 4) =
          *(const float4*)(nms_b + (((size_t)b * NCLS + cls) * MAXT + pos) * 4);
      if (s > -1.0f) vcnt++;
    }
    if (c == cls) { hh++; k = mkkey(c, hh); }
  }
  if (tid == 0) out_v[b] = (float)vcnt;
}

extern "C" void kernel_launch(void* const* d_in, const int* in_sizes, int n_in,
                              void* d_out, int out_size, void* d_ws, size_t ws_size,
                              hipStream_t stream)
{
  const float* box[5]; const float* cls[5]; const float* anc[5];
  bool interleaved = (in_sizes[1] == 2 * 57600 * 91);   // setup_inputs dict order
  if (interleaved) {
    for (int l = 0; l < 5; ++l) {
      box[l] = (const float*)d_in[3 * l + 0];
      cls[l] = (const float*)d_in[3 * l + 1];
      anc[l] = (const float*)d_in[3 * l + 2];
    }
  } else {
    for (int l = 0; l < 5; ++l) {
      box[l] = (const float*)d_in[l];
      cls[l] = (const float*)d_in[5 + l];
      anc[l] = (const float*)d_in[10 + l];
    }
  }
  const float* img = (const float*)d_in[15];

  float* ws = (float*)d_ws;
  float* boxes_ws = ws;                          // 613800 f
  float* scores_t = boxes_ws + 613800;           // 180*76736       = 13812480 f
  u32*   hist_g   = (u32*)(scores_t + 13812480); // 180*4096        = 737280 u32
  u32*   cntA_g   = hist_g + 737280;             // 180
  u32*   cntE_g   = cntA_g + 180;                // 180
  u32*   B_g      = cntE_g + 180;                // 180
  u64*   listA_g  = (u64*)(B_g + 180);           // 180*5120 u64
  u64*   listE_g  = listA_g + 180 * 5120;        // 180*2048 u64
  float* nms_s    = (float*)(listE_g + 180 * 2048);  // 18000 f
  float* nms_b    = nms_s + 18000;               // 72000 f

  decode_kernel<<<600, 256, 0, stream>>>(
      box[0], box[1], box[2], box[3], box[4],
      anc[0], anc[1], anc[2], anc[3], anc[4], img, boxes_ws, hist_g, scores_t);

  transpose_kernel<<<2402, 256, 0, stream>>>(cls[0], cls[1], cls[2], cls[3], cls[4], scores_t);

  hist_kernel<<<720, 512, 0, stream>>>(scores_t, hist_g);

  collect_kernel<<<720, 512, 0, stream>>>(scores_t, hist_g, listA_g, listE_g,
                                          cntA_g, cntE_g, B_g);

  nms_kernel<<<180, NTH, 0, stream>>>(scores_t, boxes_ws, listA_g, listE_g,
                                      cntA_g, cntE_g, B_g, nms_s, nms_b);

  float* out_b = (float*)d_out;  // [2][100][4]
  float* out_s = out_b + 800;    // [2][100]
  float* out_c = out_s + 200;    // [2][100]
  float* out_v = out_c + 200;    // [2]
  merge_kernel<<<2, 128, 0, stream>>>(nms_s, nms_b, out_b, out_s, out_c, out_v);
}

// Round 6
// 172.708 us; speedup vs baseline: 7.5961x; 1.2438x over previous
//
#include <hip/hip_runtime.h>
#include <hip/hip_bf16.h>

typedef unsigned long long u64;
typedef unsigned int u32;

#define A_TOTAL 76725
#define A_PAD   76736            /* padded to /4 for float4 loads */
#define QCH     (A_PAD / 4)
#define NCLS 90
#define KTOP 5000u
#define MAXT 100
#define KTHR 0x3D4CCCCDu         /* bits of 0.05f */
#define NTH  256                 /* nms threads */

__device__ __forceinline__ u64 pack_key(u32 k, u32 i) {
  return ((u64)k << 32) | (u64)(0xFFFFFFFFu - i);
}

// Legacy cutoff scan used by collect (wave 0). Smallest bucket B with sum(b>=B) >= need.
__device__ __forceinline__ u32 scan_cut(const u32* gh, u32 need, int tid) {
  int base = 4095 - tid * 64;
  u32 s = 0;
  #pragma unroll
  for (int j = 0; j < 64; ++j) s += gh[base - j];
  u32 incl = s;
  #pragma unroll
  for (int off = 1; off < 64; off <<= 1) {
    u32 o = __shfl_up(incl, off, 64);
    if (tid >= off) incl += o;
  }
  u32 excl = incl - s;
  bool cross = (excl < need) && (incl >= need);
  u64 bal = __ballot(cross);
  int cl = __ffsll((unsigned long long)bal) - 1;
  int cbase = 4095 - cl * 64;
  u32 cexcl = __shfl(excl, cl, 64);
  u32 v = gh[cbase - tid];
  u32 incl2 = v;
  #pragma unroll
  for (int off = 1; off < 64; off <<= 1) {
    u32 o = __shfl_up(incl2, off, 64);
    if (tid >= off) incl2 += o;
  }
  bool c2 = (cexcl + incl2 >= need) && (cexcl + incl2 - v < need);
  u64 bal2 = __ballot(c2);
  int j2 = __ffsll((unsigned long long)bal2) - 1;
  return (u32)(cbase - j2);
}

// Full wave-0 cut with totals: B = smallest bucket with count(>=B) >= need.
// incl = count(>=B), above = count(>B), total = count(all). Valid only if total >= need,
// otherwise returns total and caller must branch.
__device__ __forceinline__ void cut4096w(const u32* hh, u32 need, int wl,
                                         u32& B, u32& incl, u32& above, u32& total) {
  int lo = wl << 6;
  u32 s = 0;
  #pragma unroll
  for (int j = 0; j < 64; ++j) s += hh[lo + j];
  u32 suf = s;
  #pragma unroll
  for (int off = 1; off < 64; off <<= 1) {
    u32 v = __shfl_down(suf, off, 64);
    if (wl < 64 - off) suf += v;
  }
  total = __shfl(suf, 0, 64);
  if (total < need) { B = 0; incl = total; above = 0; return; }
  u32 sufnext = suf - s;
  bool cross = (suf >= need) && (sufnext < need);
  u64 bal = __ballot(cross);
  int gl = (int)__ffsll((unsigned long long)bal) - 1;
  int glo = gl << 6;
  u32 aboveG = __shfl(sufnext, gl, 64);
  u32 hb = hh[glo + wl];
  u32 sufb = hb;
  #pragma unroll
  for (int off = 1; off < 64; off <<= 1) {
    u32 v = __shfl_down(sufb, off, 64);
    if (wl < 64 - off) sufb += v;
  }
  bool c2 = (aboveG + sufb >= need) && (aboveG + sufb - hb < need);
  u64 bal2 = __ballot(c2);
  int jB = (int)__ffsll((unsigned long long)bal2) - 1;
  B = (u32)(glo + jB);
  incl = aboveG + __shfl(sufb, jB, 64);
  above = incl - __shfl(hb, jB, 64);
}

// Block-cooperative descending bitonic sort of a[0..n) padded to pow2 with 0.
__device__ __forceinline__ void bitonic_desc(u64* a, u32 n, int tid, int nth) {
  u32 P = 2; while (P < n) P <<= 1;
  for (u32 i = tid; i < P; i += nth) if (i >= n) a[i] = 0ULL;
  __syncthreads();
  for (u32 kk = 2; kk <= P; kk <<= 1) {
    for (u32 jj = kk >> 1; jj; jj >>= 1) {
      for (u32 i = tid; i < P; i += nth) {
        u32 ixj = i ^ jj;
        if (ixj > i) {
          u64 x = a[i], y = a[ixj];
          bool up = ((i & kk) == 0);
          if (up ? (x < y) : (x > y)) { a[i] = y; a[ixj] = x; }
        }
      }
      __syncthreads();
    }
  }
}

// ---------------- decode + clip (+ zero hist/counters/pad) ----------------
__global__ __launch_bounds__(256) void decode_kernel(
    const float* __restrict__ bx0, const float* __restrict__ bx1, const float* __restrict__ bx2,
    const float* __restrict__ bx3, const float* __restrict__ bx4,
    const float* __restrict__ an0, const float* __restrict__ an1, const float* __restrict__ an2,
    const float* __restrict__ an3, const float* __restrict__ an4,
    const float* __restrict__ img, float* __restrict__ boxes,
    u32* __restrict__ zero_base, float* __restrict__ scores_t)
{
  int t = blockIdx.x * blockDim.x + threadIdx.x;
  int nth = gridDim.x * blockDim.x;
  for (int i = t; i < 180 * 4096 + 540; i += nth) zero_base[i] = 0;
  if (t < 180 * (A_PAD - A_TOTAL)) {
    int lane = t / (A_PAD - A_TOTAL), off = t % (A_PAD - A_TOTAL);
    scores_t[(size_t)lane * A_PAD + A_TOTAL + off] = 0.0f;
  }
  if (t >= 2 * A_TOTAL) return;
  int b = t / A_TOTAL, a = t % A_TOTAL;
  const float* bp; const float* ap; int al; int nl;
  if (a < 57600)      { bp = bx0; ap = an0; al = a;          nl = 57600; }
  else if (a < 72000) { bp = bx1; ap = an1; al = a - 57600;  nl = 14400; }
  else if (a < 75600) { bp = bx2; ap = an2; al = a - 72000;  nl = 3600;  }
  else if (a < 76500) { bp = bx3; ap = an3; al = a - 75600;  nl = 900;   }
  else                { bp = bx4; ap = an4; al = a - 76500;  nl = 225;   }
  float4 e  = *(const float4*)(bp + ((size_t)b * nl + al) * 4);
  float4 an = *(const float4*)(ap + ((size_t)b * nl + al) * 4);
  const float CLIP = 4.135166556742356f; // log(1000/16)
  float ah  = an.z - an.x + 1.0f;
  float aw  = an.w - an.y + 1.0f;
  float ayc = an.x + 0.5f * ah;
  float axc = an.y + 0.5f * aw;
  float dh = fminf(e.z, CLIP), dw = fminf(e.w, CLIP);
  float yc = e.x * ah + ayc;
  float xc = e.y * aw + axc;
  float h  = expf(dh) * ah;
  float w  = expf(dw) * aw;
  float ymin = yc - 0.5f * h;
  float xmin = xc - 0.5f * w;
  float ymax = ymin + h - 1.0f;
  float xmax = xmin + w - 1.0f;
  float H = img[b * 2 + 0], W = img[b * 2 + 1];
  float4 o;
  o.x = fminf(fmaxf(ymin, 0.0f), H);
  o.y = fminf(fmaxf(xmin, 0.0f), W);
  o.z = fminf(fmaxf(ymax, 0.0f), H);
  o.w = fminf(fmaxf(xmax, 0.0f), W);
  *(float4*)(boxes + (size_t)t * 4) = o;
}

// ---------------- sigmoid + transpose to [B,90,A_PAD] ----------------
__global__ __launch_bounds__(256) void transpose_kernel(
    const float* __restrict__ c3, const float* __restrict__ c4, const float* __restrict__ c5,
    const float* __restrict__ c6, const float* __restrict__ c7, float* __restrict__ scores_t)
{
  __shared__ float lds[64 * 91];
  int blk = blockIdx.x;
  int lvl, local;
  if      (blk < 1800) { lvl = 0; local = blk; }
  else if (blk < 2250) { lvl = 1; local = blk - 1800; }
  else if (blk < 2364) { lvl = 2; local = blk - 2250; }
  else if (blk < 2394) { lvl = 3; local = blk - 2364; }
  else                 { lvl = 4; local = blk - 2394; }
  const int ns[5]    = {57600, 14400, 3600, 900, 225};
  const int bases[5] = {0, 57600, 72000, 75600, 76500};
  const int tl[5]    = {900, 225, 57, 15, 4};
  const float* cls = (lvl == 0) ? c3 : (lvl == 1) ? c4 : (lvl == 2) ? c5 : (lvl == 3) ? c6 : c7;
  int n = ns[lvl], base = bases[lvl], tiles = tl[lvl];
  int b = local / tiles, tile = local % tiles;
  int a0 = tile * 64;
  int cnt = n - a0; if (cnt > 64) cnt = 64;
  const float* src = cls + ((size_t)b * n + a0) * 91;
  int total = cnt * 91;
  for (int i = threadIdx.x; i < total; i += 256) lds[i] = src[i];
  __syncthreads();
  for (int j = threadIdx.x; j < NCLS * 64; j += 256) {
    int c = j >> 6, a = j & 63;
    if (a < cnt) {
      float x = lds[a * 91 + c + 1];
      scores_t[((size_t)(b * NCLS + c)) * A_PAD + base + a0 + a] = 1.0f / (1.0f + expf(-x));
    }
  }
}

// ---------------- per-lane global histograms (2x replicated vs atomic contention) ----------------
__global__ __launch_bounds__(512) void hist_kernel(const float* __restrict__ scores_t,
                                                   u32* __restrict__ hist_g)
{
  __shared__ u32 hist[8192];
  int tid = threadIdx.x;
  int lane = blockIdx.x >> 2, q = blockIdx.x & 3;
  for (int i = tid; i < 8192; i += 512) hist[i] = 0;
  __syncthreads();
  u32 par = (u32)(tid & 1);
  const float4* S4 = (const float4*)(scores_t + (size_t)lane * A_PAD + q * QCH);
  for (int i = tid; i < QCH / 4; i += 512) {
    float4 v = S4[i];
    atomicAdd(&hist[((__float_as_uint(v.x) >> 19) << 1) | par], 1u);
    atomicAdd(&hist[((__float_as_uint(v.y) >> 19) << 1) | par], 1u);
    atomicAdd(&hist[((__float_as_uint(v.z) >> 19) << 1) | par], 1u);
    atomicAdd(&hist[((__float_as_uint(v.w) >> 19) << 1) | par], 1u);
  }
  __syncthreads();
  u32* gh = hist_g + (size_t)lane * 4096;
  for (int i = tid; i < 4096; i += 512) {
    u32 v = hist[2 * i] + hist[2 * i + 1];
    if (v) atomicAdd(&gh[i], v);
  }
}

// ---------------- collect candidates into per-lane global lists ----------------
__global__ __launch_bounds__(512) void collect_kernel(
    const float* __restrict__ scores_t, const u32* __restrict__ hist_g,
    u64* __restrict__ listA_g, u64* __restrict__ listE_g,
    u32* __restrict__ cntA_g, u32* __restrict__ cntE_g, u32* __restrict__ B_g)
{
  __shared__ u64 bufA[5120];
  __shared__ u64 bufE[2048];
  __shared__ u32 sh_B, sh_cA, sh_cE, sh_baseA, sh_baseE;
  int tid = threadIdx.x;
  int lane = blockIdx.x >> 2, q = blockIdx.x & 3;
  const u32* gh = hist_g + (size_t)lane * 4096;
  if (tid < 64) {
    u32 B = scan_cut(gh, KTOP, tid);
    if (tid == 0) { sh_B = B; sh_cA = 0; sh_cE = 0; }
  }
  __syncthreads();
  u32 B = sh_B;
  if (tid == 0 && q == 0) B_g[lane] = B;
  const float4* S4 = (const float4*)(scores_t + (size_t)lane * A_PAD + q * QCH);
  int base_idx = q * QCH;
  for (int i = tid; i < QCH / 4; i += 512) {
    float4 v = S4[i];
    u32 ks[4] = {__float_as_uint(v.x), __float_as_uint(v.y), __float_as_uint(v.z), __float_as_uint(v.w)};
    #pragma unroll
    for (int j = 0; j < 4; ++j) {
      u32 k = ks[j], bkt = k >> 19;
      u32 idx = (u32)(base_idx + i * 4 + j);
      if (bkt > B) {
        u32 p = atomicAdd(&sh_cA, 1u);
        if (p < 5120u) bufA[p] = pack_key(k, idx);
      } else if (bkt == B) {
        u32 p = atomicAdd(&sh_cE, 1u);
        if (p < 2048u) bufE[p] = pack_key(k, idx);
      }
    }
  }
  __syncthreads();
  u32 cA = sh_cA; if (cA > 5120u) cA = 5120u;
  u32 cE = sh_cE; if (cE > 2048u) cE = 2048u;
  if (tid == 0) {
    sh_baseA = atomicAdd(&cntA_g[lane], sh_cA);
    sh_baseE = atomicAdd(&cntE_g[lane], sh_cE);
  }
  __syncthreads();
  u32 bA = sh_baseA, bE = sh_baseE;
  u64* LA = listA_g + (size_t)lane * 5120;
  u64* LE = listE_g + (size_t)lane * 2048;
  for (u32 i = tid; i < cA; i += 512) { u32 d = bA + i; if (d < 5120u) LA[d] = bufA[i]; }
  for (u32 i = tid; i < cE; i += 512) { u32 d = bE + i; if (d < 2048u) LE[d] = bufE[i]; }
}

// ---------------- per-lane NMS: affine counting-sort chunk + wave-0 lazy greedy scan ----------------
__global__ __launch_bounds__(NTH) void nms_kernel(
    const float* __restrict__ scores_t, const float* __restrict__ boxes,
    u64* __restrict__ listA_g, u64* __restrict__ listE_g,
    const u32* __restrict__ cntA_g, const u32* __restrict__ cntE_g, const u32* __restrict__ B_g,
    float* __restrict__ nms_s, float* __restrict__ nms_b)
{
  __shared__ u64 key_s[2048];                   // 16 KB sorted chunk keys
  __shared__ __align__(16) float4 box_s[2048];  // 32 KB chunk boxes; scratch u32[8192] during build
  __shared__ u64 ebuf[2048];                    // 16 KB: histL u32[4096] / listE
  __shared__ float4 wbox[MAXT];
  __shared__ u32 wtot[4];
  __shared__ u64 sh_minPrev;
  __shared__ u32 sh_w, sh_done, sh_eidx, sh_Rthr, sh_eSorted, sh_big;
  __shared__ u32 sh_B, sh_incl, sh_above, sh_total;
  __shared__ u32 sh_c0, sh_c1, sh_B2;

  u32* histL  = (u32*)ebuf;
  u32* cntArr = (u32*)box_s;

  int tid = threadIdx.x;
  int lane = blockIdx.x;
  int b = lane / NCLS;
  const float4* boxes4 = (const float4*)boxes;
  size_t bbase = (size_t)b * A_TOTAL;
  const u64 thrpack = ((u64)KTHR) << 32;

  u32 g = cntA_g[lane];
  u32 h = cntE_g[lane];
  u32 B = B_g[lane];
  u64* LAm = listA_g + (size_t)lane * 5120;
  u64* LEg = listE_g + (size_t)lane * 2048;

  if (tid == 0) {
    sh_w = 0; sh_done = 0; sh_eidx = 0; sh_eSorted = 0; sh_minPrev = ~0ull;
  }

  // ---- rare: global listE overflowed -> refine boundary on bits [18:7], spill listE ----
  if (h > 2048u) {
    const float* S = scores_t + (size_t)lane * A_PAD;
    for (int i = tid; i < 4096; i += NTH) histL[i] = 0;
    if (tid == 0) { sh_c0 = 0; sh_c1 = 0; }
    __syncthreads();
    for (int i = tid; i < A_PAD; i += NTH) {
      u32 k = __float_as_uint(S[i]);
      if ((k >> 19) == B) atomicAdd(&histL[(k >> 7) & 0xFFFu], 1u);
    }
    __syncthreads();
    u32 R1 = KTOP - g;
    if (tid < 64) {
      u32 Bx, ix, ax, tx;
      cut4096w(histL, R1, tid, Bx, ix, ax, tx);
      if (tid == 0) sh_B2 = Bx;
    }
    __syncthreads();
    u32 B2 = sh_B2;
    __syncthreads();   // histL reads done before ebuf reused as listE
    for (int i = tid; i < A_PAD; i += NTH) {
      u32 k = __float_as_uint(S[i]);
      if ((k >> 19) == B) {
        u32 sb = (k >> 7) & 0xFFFu;
        if (sb > B2) {
          u32 p = atomicAdd(&sh_c0, 1u);
          if (g + p < 5120u) LAm[g + p] = pack_key(k, (u32)i);
        } else if (sb == B2) {
          u32 p = atomicAdd(&sh_c1, 1u);
          if (p < 2048u) ebuf[p] = pack_key(k, (u32)i);
        }
      }
    }
    __syncthreads();
    g += sh_c0; if (g > 5120u) g = 5120u;
    h = sh_c1;  if (h > 2048u) h = 2048u;
    for (u32 i = tid; i < h; i += NTH) LEg[i] = ebuf[i];   // spill (syncthreads drains vmem)
    __syncthreads();
  }
  g = (g > 5120u) ? 5120u : g;
  u32 R = (g < KTOP) ? (KTOP - g) : 0u;
  if (R > h) R = h;

  // ---- listA keys -> registers (threshold-filtered; 0 = empty) ----
  u64 ak[20];
  #pragma unroll
  for (int r = 0; r < 20; ++r) {
    u32 s = (u32)tid + (u32)r * NTH;
    u64 kp = (s < g) ? LAm[s] : 0ull;
    if (kp < thrpack) kp = 0ull;
    ak[r] = kp;
  }

  float* outS = nms_s + (size_t)lane * MAXT;
  float* outB = nms_b + (size_t)lane * MAXT * 4;

  const float LO0  = 0.04f;
  const float INV0 = 4096.0f / (1.001f - 0.04f);

  // ================= segment loop =================
  for (int seg = 0; seg < 7200; ++seg) {
    __syncthreads();
    if (sh_w >= MAXT || sh_done) break;
    u64 minPrev = sh_minPrev;

    // ---- cut descent ----
    int digLvl = 0;
    u32 A_B0 = 0, A_B1 = 0;
    float lo1 = 0.f, inv1 = 0.f;
    u64 kMask = 0, kPref = 0;
    int m1shift = 32;
    int selMode = -1;          // 0=all, 1=keep boundary (d>=B), 2=above only (d>B)
    u32 selB = 0;
    u32 C = 0;
    bool fromE = false;

    for (int lvl = 0; lvl < 8; ++lvl) {
      for (int i = tid; i < 4096; i += NTH) histL[i] = 0;
      __syncthreads();
      #pragma unroll
      for (int r = 0; r < 20; ++r) {
        u64 k = ak[r];
        if (!k || k >= minPrev) continue;
        float s = __uint_as_float((u32)(k >> 32));
        if (digLvl >= 1) { int d0 = (int)((s - LO0) * INV0); d0 = min(max(d0, 0), 4095); if ((u32)d0 != A_B0) continue; }
        if (digLvl >= 2) { int d1 = (int)((s - lo1) * inv1); d1 = min(max(d1, 0), 4095); if ((u32)d1 != A_B1) continue; }
        if (digLvl >= 3 && ((k & kMask) != kPref)) continue;
        u32 d;
        if (digLvl == 0)      { int t0 = (int)((s - LO0) * INV0); d = (u32)min(max(t0, 0), 4095); }
        else if (digLvl == 1) { int t1 = (int)((s - lo1) * inv1); d = (u32)min(max(t1, 0), 4095); }
        else                  d = (u32)((k >> m1shift) & 0xFFFull);
        atomicAdd(&histL[d], 1u);
      }
      __syncthreads();
      if (tid < 64) {
        u32 Bx, ix, ax, tx;
        cut4096w(histL, 1024u, tid, Bx, ix, ax, tx);
        if (tid == 0) { sh_B = Bx; sh_incl = ix; sh_above = ax; sh_total = tx; }
      }
      __syncthreads();
      u32 total = sh_total, incl = sh_incl, above = sh_above, Bx = sh_B;
      if (total == 0u)   { fromE = true; break; }
      if (total < 1024u) { selMode = 0; C = total; break; }
      if (incl <= 2048u) { selMode = 1; selB = Bx; C = incl; break; }
      if (above > 0u)    { selMode = 2; selB = Bx; C = above; break; }
      // descend into fat bucket Bx
      if (digLvl == 0) {
        A_B0 = Bx;
        lo1 = LO0 + (float)Bx / INV0;
        inv1 = INV0 * 4096.0f;
        digLvl = 1;
      } else if (digLvl == 1) {
        A_B1 = Bx;
        digLvl = 2; m1shift = 32;
      } else {
        kPref |= ((u64)Bx << m1shift);
        kMask |= (0xFFFull << m1shift);
        m1shift -= 12;
        digLvl++;
      }
      __syncthreads();
    }

    if (fromE) {
      // ---- listA exhausted: consume sorted listE top-R ----
      if (!sh_eSorted) {
        for (u32 i = tid; i < h; i += NTH) ebuf[i] = LEg[i];
        __syncthreads();
        bitonic_desc(ebuf, h, tid, NTH);
        for (u32 i = tid; i < h; i += NTH) LEg[i] = ebuf[i];   // spill sorted
        if (tid == 0) {
          u32 lo = 0, hi2 = h;
          while (lo < hi2) { u32 mid = (lo + hi2) >> 1; if (ebuf[mid] >= thrpack) lo = mid + 1; else hi2 = mid; }
          sh_Rthr = (R < lo) ? R : lo;
          sh_eSorted = 1;
        }
        __syncthreads();
      }
      u32 eidx = sh_eidx;
      u32 take = (sh_Rthr > eidx) ? (sh_Rthr - eidx) : 0u;
      if (take > 2048u) take = 2048u;
      if (take == 0u) { if (tid == 0) sh_done = 1; continue; }
      for (u32 i = tid; i < take; i += NTH) key_s[i] = LEg[eidx + i];
      C = take;
      if (tid == 0) sh_eidx = eidx + take;
    } else {
      // ---- prefix bases in-place over histL (descending exclusive) ----
      u32 hloc[16];
      {
        int t0 = tid << 4;
        u32 ssum = 0;
        #pragma unroll
        for (int j = 0; j < 16; ++j) { hloc[j] = histL[t0 + j]; ssum += hloc[j]; }
        int wl = tid & 63, wid = tid >> 6;
        u32 suf = ssum;
        #pragma unroll
        for (int off = 1; off < 64; off <<= 1) {
          u32 v = __shfl_down(suf, off, 64);
          if (wl < 64 - off) suf += v;
        }
        if (wl == 0) wtot[wid] = suf;
        __syncthreads();
        u32 cross = 0;
        for (int w2 = wid + 1; w2 < 4; ++w2) cross += wtot[w2];
        u32 run = (suf - ssum) + cross;
        #pragma unroll
        for (int j = 15; j >= 0; --j) { u32 base2 = run; run += hloc[j]; histL[t0 + j] = base2; }
      }
      for (int i = tid; i < 4096; i += NTH) cntArr[i] = 0;
      if (tid == 0) sh_big = 0;
      __syncthreads();
      // ---- scatter ----
      #pragma unroll
      for (int r = 0; r < 20; ++r) {
        u64 k = ak[r];
        if (!k || k >= minPrev) continue;
        float s = __uint_as_float((u32)(k >> 32));
        if (digLvl >= 1) { int d0 = (int)((s - LO0) * INV0); d0 = min(max(d0, 0), 4095); if ((u32)d0 != A_B0) continue; }
        if (digLvl >= 2) { int d1 = (int)((s - lo1) * inv1); d1 = min(max(d1, 0), 4095); if ((u32)d1 != A_B1) continue; }
        if (digLvl >= 3 && ((k & kMask) != kPref)) continue;
        u32 d;
        if (digLvl == 0)      { int t0x = (int)((s - LO0) * INV0); d = (u32)min(max(t0x, 0), 4095); }
        else if (digLvl == 1) { int t1x = (int)((s - lo1) * inv1); d = (u32)min(max(t1x, 0), 4095); }
        else                  d = (u32)((k >> m1shift) & 0xFFFull);
        if (selMode == 1)      { if (d < selB) continue; }
        else if (selMode == 2) { if (d <= selB) continue; }
        u32 pos = histL[d] + atomicAdd(&cntArr[d], 1u);
        if (pos < 2048u) key_s[pos] = k;
      }
      __syncthreads();
      // ---- per-bucket minisort (full-key desc) ----
      {
        int t0 = tid << 4;
        for (int j = 0; j < 16; ++j) {
          u32 bkt = (u32)(t0 + j);
          u32 c = cntArr[bkt];
          if (c >= 2u) {
            if (c <= 48u) {
              u32 basep = histL[bkt];
              for (u32 a2 = 1; a2 < c; ++a2) {
                u64 kv = key_s[basep + a2];
                int bi = (int)a2 - 1;
                while (bi >= 0 && key_s[basep + bi] < kv) { key_s[basep + bi + 1] = key_s[basep + bi]; --bi; }
                key_s[basep + bi + 1] = kv;
              }
            } else sh_big = 1;
          }
        }
      }
      __syncthreads();
      if (sh_big) bitonic_desc(key_s, C, tid, NTH);
      if (tid == 0) sh_minPrev = key_s[C - 1];
    }
    __syncthreads();

    // ---- gather chunk boxes (overwrites scratch) ----
    for (u32 p = tid; p < C; p += NTH) {
      u32 idx = 0xFFFFFFFFu - (u32)(key_s[p] & 0xFFFFFFFFull);
      box_s[p] = boxes4[bbase + idx];
    }
    __syncthreads();

    // ---- lazy greedy scan (wave 0 only, no barriers) ----
    if (tid < 64) {
      int wl = tid;
      int w = (int)sh_w;
      u32 cur = 0;
      while (w < MAXT && cur < C) {
        u32 p = cur + (u32)wl;
        bool aliveL = (p < C);
        u64 kk = aliveL ? key_s[p] : 0ull;
        float4 mybox;
        if (aliveL) mybox = box_s[p];
        float myarea = aliveL ? (mybox.z - mybox.x) * (mybox.w - mybox.y) : 0.f;
        for (int j = 0; j < w; ++j) {
          if (aliveL) {
            float4 pb = wbox[j];
            float yy1 = fmaxf(pb.x, mybox.x), xx1 = fmaxf(pb.y, mybox.y);
            float yy2 = fminf(pb.z, mybox.z), xx2 = fminf(pb.w, mybox.w);
            float inter = fmaxf(yy2 - yy1, 0.0f) * fmaxf(xx2 - xx1, 0.0f);
            float pa = (pb.z - pb.x) * (pb.w - pb.y);
            if (inter / (pa + myarea - inter + 1e-8f) > 0.3f) aliveL = false;
          }
        }
        for (;;) {
          u64 bal = __ballot(aliveL);
          if (bal == 0ull) break;
          int js = (int)__ffsll((unsigned long long)bal) - 1;
          float4 pb;
          pb.x = __shfl(mybox.x, js, 64);
          pb.y = __shfl(mybox.y, js, 64);
          pb.z = __shfl(mybox.z, js, 64);
          pb.w = __shfl(mybox.w, js, 64);
          u64 wk = __shfl(kk, js, 64);
          if (wl == 0) {
            outS[w] = __uint_as_float((u32)(wk >> 32));
            *(float4*)(outB + w * 4) = pb;
            wbox[w] = pb;
          }
          w++;
          if (w >= MAXT) break;
          if (wl <= js) aliveL = false;
          else if (aliveL) {
            float yy1 = fmaxf(pb.x, mybox.x), xx1 = fmaxf(pb.y, mybox.y);
            float yy2 = fminf(pb.z, mybox.z), xx2 = fminf(pb.w, mybox.w);
            float inter = fmaxf(yy2 - yy1, 0.0f) * fmaxf(xx2 - xx1, 0.0f);
            float pa = (pb.z - pb.x) * (pb.w - pb.y);
            if (inter / (pa + myarea - inter + 1e-8f) > 0.3f) aliveL = false;
          }
        }
        cur += 64;
      }
      if (wl == 0) sh_w = (u32)w;
    }
  }

  // ---- padding like reference ----
  __syncthreads();
  u32 w = sh_w;
  for (u32 p = w + (u32)tid; p < MAXT; p += NTH) {
    outS[p] = -1.0f;
    *(float4*)(outB + p * 4) = make_float4(0.f, 0.f, 0.f, 0.f);
  }
}

// ---------------- final per-batch top-100: radix rank-select (no serial loop) ----------------
__global__ __launch_bounds__(256) void merge_kernel(
    const float* __restrict__ nms_s, const float* __restrict__ nms_b,
    float* __restrict__ out_b, float* __restrict__ out_s,
    float* __restrict__ out_c, float* __restrict__ out_v)
{
  __shared__ u64 keys[NCLS * MAXT];   // 72 KB
  __shared__ u32 hist[4096];          // 16 KB
  __shared__ u64 sel[640];
  __shared__ u32 sh_cnt, sh_valid;
  __shared__ u32 sh_B, sh_incl, sh_above, sh_total;

  int b = blockIdx.x, tid = threadIdx.x;
  const int NTOT = NCLS * MAXT;

  // build orderable keys: (transformed score << 32) | ~flat  — all unique
  for (int i = tid; i < NTOT; i += 256) {
    float s = nms_s[(size_t)b * NTOT + i];
    u32 u = __float_as_uint(s);
    u = (u & 0x80000000u) ? ~u : (u | 0x80000000u);
    keys[i] = ((u64)u << 32) | (u64)(0xFFFFFFFFu - (u32)i);
  }
  if (tid == 0) { sh_cnt = 0; sh_valid = 0; }

  // radix descent: 12-bit digits at shifts 52,40,28,16,4 then 4-bit at 0.
  // Invariant: winners = {k >= T}; terminates because keys are unique.
  u64 prefVal = 0;
  u64 T = 0;
  u32 need = MAXT;
  const int shifts[6] = {52, 40, 28, 16, 4, 0};
  const int widths[6] = {12, 12, 12, 12, 12, 4};
  for (int lvl = 0; lvl < 6; ++lvl) {
    int s = shifts[lvl], w = widths[lvl];
    for (int i = tid; i < 4096; i += 256) hist[i] = 0;
    __syncthreads();
    u32 dmask = (1u << w) - 1u;
    for (int i = tid; i < NTOT; i += 256) {
      u64 k = keys[i];
      if (lvl > 0 && (k >> (s + w)) != (prefVal >> (s + w))) continue;
      atomicAdd(&hist[(u32)((k >> s) & dmask)], 1u);
    }
    __syncthreads();
    if (tid < 64) {
      u32 Bx, ix, ax, tx;
      cut4096w(hist, need, tid, Bx, ix, ax, tx);
      if (tid == 0) { sh_B = Bx; sh_incl = ix; sh_above = ax; sh_total = tx; }
    }
    __syncthreads();
    u32 B = sh_B, incl = sh_incl, above = sh_above;
    if (incl <= 512u || lvl == 5) {
      T = prefVal | ((u64)B << s);
      break;
    }
    prefVal |= ((u64)B << s);
    need -= above;
  }
  __syncthreads();

  // collect {k >= T}: count = (MAXT - need_final) + incl_final <= 99 + 512 < 640
  for (int i = tid; i < NTOT; i += 256) {
    u64 k = keys[i];
    if (k >= T) {
      u32 p = atomicAdd(&sh_cnt, 1u);
      if (p < 640u) sel[p] = k;
    }
  }
  __syncthreads();
  u32 cnt = sh_cnt; if (cnt > 640u) cnt = 640u;

  // rank-by-comparison (unique keys -> perfect permutation); write rows r < 100
  for (u32 j = tid; j < cnt; j += 256) {
    u64 kj = sel[j];
    u32 r = 0;
    for (u32 i = 0; i < cnt; ++i) r += (sel[i] > kj) ? 1u : 0u;
    if (r < (u32)MAXT) {
      u32 u = (u32)(kj >> 32);
      u32 bits = (u & 0x80000000u) ? (u ^ 0x80000000u) : ~u;
      float sc = __uint_as_float(bits);
      u32 flat = 0xFFFFFFFFu - (u32)(kj & 0xFFFFFFFFull);
      int cls = (int)(flat / MAXT), pos = (int)(flat % MAXT);
      out_s[b * MAXT + r] = sc;
      out_c[b * MAXT + r] = (float)(cls + 1);
      *(float4*)(out_b + ((size_t)b * MAXT + r) * 4) =
          *(const float4*)(nms_b + (((size_t)b * NCLS + cls) * MAXT + pos) * 4);
      if (sc > -1.0f) atomicAdd(&sh_valid, 1u);
    }
  }
  __syncthreads();
  if (tid == 0) out_v[b] = (float)sh_valid;
}

extern "C" void kernel_launch(void* const* d_in, const int* in_sizes, int n_in,
                              void* d_out, int out_size, void* d_ws, size_t ws_size,
                              hipStream_t stream)
{
  const float* box[5]; const float* cls[5]; const float* anc[5];
  bool interleaved = (in_sizes[1] == 2 * 57600 * 91);   // setup_inputs dict order
  if (interleaved) {
    for (int l = 0; l < 5; ++l) {
      box[l] = (const float*)d_in[3 * l + 0];
      cls[l] = (const float*)d_in[3 * l + 1];
      anc[l] = (const float*)d_in[3 * l + 2];
    }
  } else {
    for (int l = 0; l < 5; ++l) {
      box[l] = (const float*)d_in[l];
      cls[l] = (const float*)d_in[5 + l];
      anc[l] = (const float*)d_in[10 + l];
    }
  }
  const float* img = (const float*)d_in[15];

  float* ws = (float*)d_ws;
  float* boxes_ws = ws;                          // 613800 f
  float* scores_t = boxes_ws + 613800;           // 180*76736       = 13812480 f
  u32*   hist_g   = (u32*)(scores_t + 13812480); // 180*4096        = 737280 u32
  u32*   cntA_g   = hist_g + 737280;             // 180
  u32*   cntE_g   = cntA_g + 180;                // 180
  u32*   B_g      = cntE_g + 180;                // 180
  u64*   listA_g  = (u64*)(B_g + 180);           // 180*5120 u64
  u64*   listE_g  = listA_g + 180 * 5120;        // 180*2048 u64
  float* nms_s    = (float*)(listE_g + 180 * 2048);  // 18000 f
  float* nms_b    = nms_s + 18000;               // 72000 f

  decode_kernel<<<600, 256, 0, stream>>>(
      box[0], box[1], box[2], box[3], box[4],
      anc[0], anc[1], anc[2], anc[3], anc[4], img, boxes_ws, hist_g, scores_t);

  transpose_kernel<<<2402, 256, 0, stream>>>(cls[0], cls[1], cls[2], cls[3], cls[4], scores_t);

  hist_kernel<<<720, 512, 0, stream>>>(scores_t, hist_g);

  collect_kernel<<<720, 512, 0, stream>>>(scores_t, hist_g, listA_g, listE_g,
                                          cntA_g, cntE_g, B_g);

  nms_kernel<<<180, NTH, 0, stream>>>(scores_t, boxes_ws, listA_g, listE_g,
                                      cntA_g, cntE_g, B_g, nms_s, nms_b);

  float* out_b = (float*)d_out;  // [2][100][4]
  float* out_s = out_b + 800;    // [2][100]
  float* out_c = out_s + 200;    // [2][100]
  float* out_v = out_c + 200;    // [2]
  merge_kernel<<<2, 256, 0, stream>>>(nms_s, nms_b, out_b, out_s, out_c, out_v);
}